// Round 1
// baseline (518.175 us; speedup 1.0000x reference)
//
#include <hip/hip_runtime.h>
#include <math.h>

#define TPB 256

// Problem constants: B=8, Ch=256, Cl=128, H=W=64, N=4096, r=64, M2=2048, HID=16
constexpr int BATCH = 8;
constexpr int CH    = 256;
constexpr int CL    = 128;
constexpr int NPIX  = 4096;   // 64*64
constexpr int HID   = 16;

// ---------------------------------------------------------------------------
// Generic fp32 NN GEMM: C[b] = A[b] * B[b] (+bias), optional BN+residual epi.
// A: [M,K] row-major, per-batch stride sA (0 => shared weights)
// B: [K,N] row-major, per-batch stride sB
// C: [M,N] row-major, per-batch stride sC
// epi==1: C = (gemm+bias)*scale[row] + shift[row] + res[b,row,col]
// ---------------------------------------------------------------------------
__global__ __launch_bounds__(TPB)
void gemm_nn(const float* __restrict__ A, long long sA,
             const float* __restrict__ B, long long sB,
             float* __restrict__ C, long long sC,
             const float* __restrict__ bias,
             int M, int N, int K, int epi,
             const float* __restrict__ bng, const float* __restrict__ bnb,
             const float* __restrict__ bnm, const float* __restrict__ bnv,
             const float* __restrict__ res, long long sR)
{
    constexpr int BM = 64, BN = 64, BK = 16, TM = 4, TN = 4;
    __shared__ float As[BK][BM + 4];
    __shared__ float Bs[BK][BN];
    const int b = blockIdx.z;
    const float* Ab = A + (size_t)b * sA;
    const float* Bb = B + (size_t)b * sB;
    float* Cb = C + (size_t)b * sC;
    const int mBase = blockIdx.y * BM;
    const int nBase = blockIdx.x * BN;
    const int tid = threadIdx.x;
    const int tx = tid & 15, ty = tid >> 4;

    float acc[TM][TN];
#pragma unroll
    for (int i = 0; i < TM; ++i)
#pragma unroll
        for (int j = 0; j < TN; ++j) acc[i][j] = 0.f;

    for (int k0 = 0; k0 < K; k0 += BK) {
#pragma unroll
        for (int l = 0; l < (BM * BK) / TPB; ++l) {
            int idx = tid + l * TPB;
            int m = idx >> 4, k = idx & 15;
            As[k][m] = Ab[(size_t)(mBase + m) * K + k0 + k];
        }
#pragma unroll
        for (int l = 0; l < (BK * BN) / TPB; ++l) {
            int idx = tid + l * TPB;
            int k = idx >> 6, n = idx & 63;
            Bs[k][n] = Bb[(size_t)(k0 + k) * N + nBase + n];
        }
        __syncthreads();
#pragma unroll
        for (int k = 0; k < BK; ++k) {
            float ra[TM], rb[TN];
#pragma unroll
            for (int i = 0; i < TM; ++i) ra[i] = As[k][ty * TM + i];
#pragma unroll
            for (int j = 0; j < TN; ++j) rb[j] = Bs[k][tx * TN + j];
#pragma unroll
            for (int i = 0; i < TM; ++i)
#pragma unroll
                for (int j = 0; j < TN; ++j) acc[i][j] += ra[i] * rb[j];
        }
        __syncthreads();
    }

#pragma unroll
    for (int i = 0; i < TM; ++i) {
        int row = mBase + ty * TM + i;
        float bi = bias ? bias[row] : 0.f;
        float scale = 1.f, shift = 0.f;
        if (epi == 1) {
            scale = bng[row] * rsqrtf(bnv[row] + 1e-5f);
            shift = bnb[row] - bnm[row] * scale;
        }
#pragma unroll
        for (int j = 0; j < TN; ++j) {
            int col = nBase + tx * TN + j;
            float v = acc[i][j] + bi;
            if (epi == 1)
                v = v * scale + shift + res[(size_t)b * sR + (size_t)row * N + col];
            Cb[(size_t)row * N + col] = v;
        }
    }
}

// ---------------------------------------------------------------------------
// NT GEMM with split-K + atomicAdd: C[b][m,d] += alpha * sum_k A[b][m,k]*B[b][d,k]
// A: [M,K] row-major per batch; B: [Nd,K] row-major per batch; C: [M,Nd].
// grid.z = BATCH * nChunks. C must be zeroed beforehand.
// ---------------------------------------------------------------------------
__global__ __launch_bounds__(TPB)
void gemm_nt_splitk(const float* __restrict__ A, long long sA,
                    const float* __restrict__ B, long long sB,
                    float* __restrict__ C, long long sC,
                    int M, int Nd, int K, int nChunks, float alpha)
{
    constexpr int BM = 64, BN = 64, BK = 16, TM = 4, TN = 4;
    __shared__ float As[BK][BM + 4];
    __shared__ float Bs[BK][BN + 4];
    const int chunk = blockIdx.z % nChunks;
    const int b     = blockIdx.z / nChunks;
    const int kLen  = K / nChunks;
    const int kBeg  = chunk * kLen;
    const float* Ab = A + (size_t)b * sA;
    const float* Bb = B + (size_t)b * sB;
    float* Cb = C + (size_t)b * sC;
    const int mBase = blockIdx.y * BM;
    const int nBase = blockIdx.x * BN;
    const int tid = threadIdx.x;
    const int tx = tid & 15, ty = tid >> 4;

    float acc[TM][TN];
#pragma unroll
    for (int i = 0; i < TM; ++i)
#pragma unroll
        for (int j = 0; j < TN; ++j) acc[i][j] = 0.f;

    for (int k0 = kBeg; k0 < kBeg + kLen; k0 += BK) {
#pragma unroll
        for (int l = 0; l < (BM * BK) / TPB; ++l) {
            int idx = tid + l * TPB;
            int m = idx >> 4, k = idx & 15;
            As[k][m] = Ab[(size_t)(mBase + m) * K + k0 + k];
        }
#pragma unroll
        for (int l = 0; l < (BN * BK) / TPB; ++l) {
            int idx = tid + l * TPB;
            int d = idx >> 4, k = idx & 15;
            Bs[k][d] = Bb[(size_t)(nBase + d) * K + k0 + k];
        }
        __syncthreads();
#pragma unroll
        for (int k = 0; k < BK; ++k) {
            float ra[TM], rb[TN];
#pragma unroll
            for (int i = 0; i < TM; ++i) ra[i] = As[k][ty * TM + i];
#pragma unroll
            for (int j = 0; j < TN; ++j) rb[j] = Bs[k][tx * TN + j];
#pragma unroll
            for (int i = 0; i < TM; ++i)
#pragma unroll
                for (int j = 0; j < TN; ++j) acc[i][j] += ra[i] * rb[j];
        }
        __syncthreads();
    }

#pragma unroll
    for (int i = 0; i < TM; ++i) {
        int row = mBase + ty * TM + i;
#pragma unroll
        for (int j = 0; j < TN; ++j) {
            int col = nBase + tx * TN + j;
            atomicAdd(&Cb[(size_t)row * Nd + col], alpha * acc[i][j]);
        }
    }
}

__global__ void zero_f32(float* p, int n)
{
    int i = blockIdx.x * TPB + threadIdx.x;
    if (i < n) p[i] = 0.f;
}

// mean & max over the 4096 spatial positions, per (b,c)
__global__ __launch_bounds__(TPB)
void spatial_mean_max(const float* __restrict__ z, float* __restrict__ avg,
                      float* __restrict__ mx)
{
    const int c = blockIdx.x, b = blockIdx.y, tid = threadIdx.x;
    const float* p = z + ((size_t)b * CH + c) * NPIX;
    float s = 0.f, m = -1e30f;
    for (int n = tid; n < NPIX; n += TPB) {
        float v = p[n];
        s += v;
        m = fmaxf(m, v);
    }
    __shared__ float ss[TPB], sm[TPB];
    ss[tid] = s; sm[tid] = m;
    __syncthreads();
    for (int st = TPB / 2; st > 0; st >>= 1) {
        if (tid < st) {
            ss[tid] += ss[tid + st];
            sm[tid] = fmaxf(sm[tid], sm[tid + st]);
        }
        __syncthreads();
    }
    if (tid == 0) {
        avg[b * CH + c] = ss[0] * (1.f / NPIX);
        mx[b * CH + c]  = sm[0];
    }
}

// ca = sigmoid(fc2 * (relu(fc1*avg) + relu(fc1*mx)))  — one block per batch
__global__ __launch_bounds__(TPB)
void ca_mlp(const float* __restrict__ avg, const float* __restrict__ mx,
            const float* __restrict__ fc1, const float* __restrict__ fc2,
            float* __restrict__ ca)
{
    const int b = blockIdx.x, tid = threadIdx.x;
    __shared__ float s_avg[CH], s_mx[CH], s_h[HID];
    s_avg[tid] = avg[b * CH + tid];
    s_mx[tid]  = mx[b * CH + tid];
    __syncthreads();
    if (tid < HID) {
        float ha = 0.f, hm = 0.f;
        for (int c = 0; c < CH; ++c) {
            float w = fc1[tid * CH + c];
            ha += w * s_avg[c];
            hm += w * s_mx[c];
        }
        s_h[tid] = fmaxf(ha, 0.f) + fmaxf(hm, 0.f);
    }
    __syncthreads();
    float o = 0.f;
#pragma unroll
    for (int h = 0; h < HID; ++h) o += fc2[tid * HID + h] * s_h[h];
    ca[b * CH + tid] = 1.f / (1.f + expf(-o));
}

// sa_in[b,0,n]=mean_c(z*ca), sa_in[b,1,n]=max_c(z*ca)
__global__ __launch_bounds__(TPB)
void sa_input(const float* __restrict__ z, const float* __restrict__ ca,
              float* __restrict__ sain)
{
    const int b = blockIdx.y;
    const int n = blockIdx.x * TPB + threadIdx.x;
    const float* zb = z + (size_t)b * CH * NPIX;
    const float* cab = ca + b * CH;
    float s = 0.f, m = -1e30f;
    for (int c = 0; c < CH; ++c) {
        float v = zb[(size_t)c * NPIX + n] * cab[c];
        s += v;
        m = fmaxf(m, v);
    }
    sain[(size_t)b * 2 * NPIX + n] = s * (1.f / CH);
    sain[(size_t)b * 2 * NPIX + NPIX + n] = m;
}

// 7x7 conv, 2->1 channels, pad 3 (cross-correlation, matching jax.lax.conv)
__global__ __launch_bounds__(TPB)
void sa_conv7(const float* __restrict__ sain, const float* __restrict__ w,
              float* __restrict__ sa)
{
    __shared__ float ws[98];
    const int tid = threadIdx.x;
    if (tid < 98) ws[tid] = w[tid];
    __syncthreads();
    const int b = blockIdx.y;
    const int n = blockIdx.x * TPB + tid;
    const int h = n >> 6, x = n & 63;
    const float* p = sain + (size_t)b * 2 * NPIX;
    float s = 0.f;
#pragma unroll
    for (int ci = 0; ci < 2; ++ci)
#pragma unroll
        for (int ky = 0; ky < 7; ++ky) {
            int yy = h + ky - 3;
            if (yy < 0 || yy >= 64) continue;
#pragma unroll
            for (int kx = 0; kx < 7; ++kx) {
                int xx = x + kx - 3;
                if (xx < 0 || xx >= 64) continue;
                s += ws[ci * 49 + ky * 7 + kx] * p[ci * NPIX + yy * 64 + xx];
            }
        }
    sa[(size_t)b * NPIX + n] = s;
}

// out = fw * (z*ca*sigmoid(sa)) + (1-fw)*x
__global__ __launch_bounds__(TPB)
void fuse_out(const float* __restrict__ z, const float* __restrict__ ca,
              const float* __restrict__ sa, const float* __restrict__ x,
              const float* __restrict__ fwp, float* __restrict__ out)
{
    size_t idx = (size_t)blockIdx.x * TPB + threadIdx.x;
    int b = (int)(idx >> 20);          // 256*4096 per batch
    int rem = (int)(idx & 1048575);
    int c = rem >> 12;
    int n = rem & 4095;
    float fw = fwp[0];
    float s = 1.f / (1.f + expf(-sa[((size_t)b << 12) + n]));
    float v = z[idx] * ca[b * CH + c] * s;
    out[idx] = fw * v + (1.f - fw) * x[idx];
}

extern "C" void kernel_launch(void* const* d_in, const int* in_sizes, int n_in,
                              void* d_out, int out_size, void* d_ws, size_t ws_size,
                              hipStream_t stream)
{
    const float* x        = (const float*)d_in[0];
    const float* x0       = (const float*)d_in[1];
    const float* cnl_g_w  = (const float*)d_in[2];
    const float* cnl_g_b  = (const float*)d_in[3];
    const float* cnl_th_w = (const float*)d_in[4];
    const float* cnl_th_b = (const float*)d_in[5];
    const float* cnl_ph_w = (const float*)d_in[6];
    const float* cnl_ph_b = (const float*)d_in[7];
    const float* cnl_W_w  = (const float*)d_in[8];
    const float* cnl_W_b  = (const float*)d_in[9];
    const float* cnl_bn_g = (const float*)d_in[10];
    const float* cnl_bn_b = (const float*)d_in[11];
    const float* cnl_bn_m = (const float*)d_in[12];
    const float* cnl_bn_v = (const float*)d_in[13];
    const float* pnl_g_w  = (const float*)d_in[14];
    const float* pnl_g_b  = (const float*)d_in[15];
    const float* pnl_th_w = (const float*)d_in[16];
    const float* pnl_th_b = (const float*)d_in[17];
    const float* pnl_ph_w = (const float*)d_in[18];
    const float* pnl_ph_b = (const float*)d_in[19];
    const float* pnl_W_w  = (const float*)d_in[20];
    const float* pnl_W_b  = (const float*)d_in[21];
    const float* pnl_bn_g = (const float*)d_in[22];
    const float* pnl_bn_b = (const float*)d_in[23];
    const float* pnl_bn_m = (const float*)d_in[24];
    const float* pnl_bn_v = (const float*)d_in[25];
    const float* ca_fc1   = (const float*)d_in[26];
    const float* ca_fc2   = (const float*)d_in[27];
    const float* sa_w     = (const float*)d_in[28];
    const float* fw       = (const float*)d_in[29];
    float* out = (float*)d_out;
    float* ws  = (float*)d_ws;

    // ---- workspace layout (floats), with buffer reuse; total ~85 MB ----
    float* gx  = ws + 0;              // [8,128,4096]  (later: g2 [0..2M), t2 [2M..4M))
    float* th  = ws + 4194304;        // [8,128,4096]  (later: p2)
    float* ph  = ws + 8388608;        // [8,128,4096]  (later: y, then Y)
    float* z   = ws + 12582912;       // [8,256,4096]  z_cnl -> z_pnl in-place
    float* att = ws + 20971520;       // [8,128,128]   (later: S)
    float* avg = ws + 21102592;       // [8,256]
    float* mxb = ws + 21104640;       // [8,256]
    float* ca  = ws + 21106688;       // [8,256]
    float* sain= ws + 21108736;       // [8,2,4096]
    float* sa  = ws + 21174272;       // [8,4096]
    float* g2  = gx;                  // [8,64,4096] == view [8,128,2048]
    float* t2  = gx + 2097152;
    float* p2  = th;
    float* y   = ph;
    float* Y   = ph;

    const dim3 blk(TPB);
    const long long sX   = (long long)CH * NPIX;   // 1048576
    const long long sX0  = (long long)CL * NPIX;   // 524288
    const long long sR2  = (long long)64 * NPIX;   // 262144
    const long long sAtt = (long long)CL * CL;     // 16384

    // ---- Stage 1: CNL 1x1 convs ----
    gemm_nn<<<dim3(64, 2, 8), blk, 0, stream>>>(cnl_g_w, 0, x0, sX0, gx, sX0,
        cnl_g_b, CL, NPIX, CL, 0, nullptr, nullptr, nullptr, nullptr, nullptr, 0);
    gemm_nn<<<dim3(64, 2, 8), blk, 0, stream>>>(cnl_th_w, 0, x, sX, th, sX0,
        cnl_th_b, CL, NPIX, CH, 0, nullptr, nullptr, nullptr, nullptr, nullptr, 0);
    gemm_nn<<<dim3(64, 2, 8), blk, 0, stream>>>(cnl_ph_w, 0, x0, sX0, ph, sX0,
        cnl_ph_b, CL, NPIX, CL, 0, nullptr, nullptr, nullptr, nullptr, nullptr, 0);

    // ---- Stage 2: att[c,d] = (1/Cl) * sum_n th[c,n] ph[d,n] ----
    zero_f32<<<dim3(512), blk, 0, stream>>>(att, 8 * CL * CL);
    gemm_nt_splitk<<<dim3(2, 2, 8 * 8), blk, 0, stream>>>(th, sX0, ph, sX0,
        att, sAtt, CL, CL, NPIX, 8, 1.f / CL);

    // ---- Stage 3: y = att * g_x ----
    gemm_nn<<<dim3(64, 2, 8), blk, 0, stream>>>(att, sAtt, gx, sX0, y, sX0,
        nullptr, CL, NPIX, CL, 0, nullptr, nullptr, nullptr, nullptr, nullptr, 0);

    // ---- Stage 4: z_cnl = bn(W*y + b) + x ----
    gemm_nn<<<dim3(64, 4, 8), blk, 0, stream>>>(cnl_W_w, 0, y, sX0, z, sX,
        cnl_W_b, CH, NPIX, CL, 1, cnl_bn_g, cnl_bn_b, cnl_bn_m, cnl_bn_v, x, sX);

    // ---- Stage 5: PNL 1x1 convs (outputs viewed as [8,128,2048]) ----
    gemm_nn<<<dim3(64, 1, 8), blk, 0, stream>>>(pnl_g_w, 0, x0, sX0, g2, sR2,
        pnl_g_b, 64, NPIX, CL, 0, nullptr, nullptr, nullptr, nullptr, nullptr, 0);
    gemm_nn<<<dim3(64, 1, 8), blk, 0, stream>>>(pnl_th_w, 0, z, sX, t2, sR2,
        pnl_th_b, 64, NPIX, CH, 0, nullptr, nullptr, nullptr, nullptr, nullptr, 0);
    gemm_nn<<<dim3(64, 1, 8), blk, 0, stream>>>(pnl_ph_w, 0, x0, sX0, p2, sR2,
        pnl_ph_b, 64, NPIX, CL, 0, nullptr, nullptr, nullptr, nullptr, nullptr, 0);

    // ---- Stage 6: S = (1/2048) * G P^T ; Y = S * T   (assoc. trick: no att2) ----
    zero_f32<<<dim3(512), blk, 0, stream>>>(att, 8 * CL * CL);
    gemm_nt_splitk<<<dim3(2, 2, 8 * 8), blk, 0, stream>>>(g2, sR2, p2, sR2,
        att, sAtt, CL, CL, 2048, 8, 1.f / 2048.f);
    gemm_nn<<<dim3(32, 2, 8), blk, 0, stream>>>(att, sAtt, t2, sR2, Y, sR2,
        nullptr, CL, 2048, CL, 0, nullptr, nullptr, nullptr, nullptr, nullptr, 0);

    // ---- Stage 7: z_pnl = bn(W*y2r + b) + z_cnl  (in place over z) ----
    gemm_nn<<<dim3(64, 4, 8), blk, 0, stream>>>(pnl_W_w, 0, Y, sR2, z, sX,
        pnl_W_b, CH, NPIX, 64, 1, pnl_bn_g, pnl_bn_b, pnl_bn_m, pnl_bn_v, z, sX);

    // ---- Stage 8: CBAM channel attention ----
    spatial_mean_max<<<dim3(CH, BATCH), blk, 0, stream>>>(z, avg, mxb);
    ca_mlp<<<dim3(BATCH), blk, 0, stream>>>(avg, mxb, ca_fc1, ca_fc2, ca);

    // ---- Stage 9: spatial attention + fused output ----
    sa_input<<<dim3(16, BATCH), blk, 0, stream>>>(z, ca, sain);
    sa_conv7<<<dim3(16, BATCH), blk, 0, stream>>>(sain, sa_w, sa);
    fuse_out<<<dim3(32768), blk, 0, stream>>>(z, ca, sa, x, fw, out);
}

// Round 3
// 352.892 us; speedup vs baseline: 1.4684x; 1.4684x over previous
//
#include <hip/hip_runtime.h>
#include <math.h>

typedef unsigned short u16;
typedef unsigned int   u32;
typedef __bf16 bf16_8 __attribute__((ext_vector_type(8)));
typedef float  f32x4  __attribute__((ext_vector_type(4)));

constexpr int BATCH = 8;
constexpr int CH    = 256;
constexpr int CL    = 128;
constexpr int NPIX  = 4096;
constexpr int HID   = 16;

__device__ __forceinline__ u16 f2bf(float f) {
    u32 u = __float_as_uint(f);
    u = (u + 0x7FFFu + ((u >> 16) & 1u)) >> 16;
    return (u16)u;
}
__device__ __forceinline__ float bf2f(u16 h) { return __uint_as_float((u32)h << 16); }
__device__ __forceinline__ u32 encF(float f) {
    u32 u = __float_as_uint(f);
    return u ^ (u32)(((int)u >> 31) | 0x80000000);
}
__device__ __forceinline__ float decF(u32 u) {
    return __uint_as_float((u >> 31) ? (u ^ 0x80000000u) : ~u);
}

// ---------------------------------------------------------------------------
// Universal bf16 MFMA NT GEMM: C[b][m][n] = sum_k A[b][m][k] * B[b][n][k]
// A: [M][K] row-major bf16 (per-batch elem stride sA; 0 => shared)
// B: [N][K] row-major bf16
// modes: 0 = bf16 store (bias row- or col-indexed), 1 = atomicAdd f32 (split-K),
//        2 = T2-fold bf16 store (+col bias), 3 = Y-fold bf16 store,
//        4 = (acc+bias)*bnScale+bnShift + res(bf16), store bf16
// ---------------------------------------------------------------------------
template<int BN>
__global__ __launch_bounds__(256, 2)
void mfma_nt(const u16* __restrict__ A, long long sA, int lda,
             const u16* __restrict__ B, long long sB, int ldb,
             int K, int nSplit, int mode,
             u16* __restrict__ outB, float* __restrict__ outF,
             long long sC, int ldc,
             const float* __restrict__ bias, int biasRow,
             const float* __restrict__ bng, const float* __restrict__ bnb,
             const float* __restrict__ bnm, const float* __restrict__ bnv,
             const u16* __restrict__ resB, long long sR)
{
    constexpr int BM = 64, BK = 64;
    constexpr int WN = BN / 4;     // per-wave N span
    constexpr int NT = WN / 16;    // n-tiles per wave
    __shared__ __align__(16) u16 As[BM * BK];
    __shared__ __align__(16) u16 Bs[BN * BK];

    const int bz    = blockIdx.z;
    const int batch = bz / nSplit;
    const int split = bz % nSplit;
    const int kLen  = K / nSplit;
    const int kBeg  = split * kLen;

    const u16* Ab = A + (size_t)batch * sA;
    const u16* Bb = B + (size_t)batch * sB;

    const int mBase = blockIdx.y * BM;
    const int nBase = blockIdx.x * BN;
    const int tid   = threadIdx.x;
    const int wave  = tid >> 6;
    const int lane  = tid & 63;
    const int lm    = lane & 15;
    const int q     = lane >> 4;

    f32x4 acc[4][NT];
#pragma unroll
    for (int i = 0; i < 4; ++i)
#pragma unroll
        for (int j = 0; j < NT; ++j) acc[i][j] = f32x4{0.f, 0.f, 0.f, 0.f};

    const int srow = tid >> 3;   // 0..31
    const int sc8  = tid & 7;    // 16B chunk within 64-elem row

    for (int k0 = kBeg; k0 < kBeg + kLen; k0 += BK) {
        __syncthreads();
        // stage A tile (64 x 64), XOR-swizzled chunks for conflict-free b128 reads
#pragma unroll
        for (int it = 0; it < 2; ++it) {
            int r = srow + it * 32;
            uint4 v = *(const uint4*)(Ab + (size_t)(mBase + r) * lda + k0 + sc8 * 8);
            *(uint4*)&As[r * BK + ((sc8 ^ (r & 7)) * 8)] = v;
        }
        // stage B tile (BN x 64)
#pragma unroll
        for (int it = 0; it < BN / 32; ++it) {
            int r = srow + it * 32;
            uint4 v = *(const uint4*)(Bb + (size_t)(nBase + r) * ldb + k0 + sc8 * 8);
            *(uint4*)&Bs[r * BK + ((sc8 ^ (r & 7)) * 8)] = v;
        }
        __syncthreads();
#pragma unroll
        for (int ks = 0; ks < 2; ++ks) {
            bf16_8 af[4], bfr[NT];
#pragma unroll
            for (int mt = 0; mt < 4; ++mt) {
                int r = mt * 16 + lm;
                af[mt] = *(const bf16_8*)&As[r * BK + (((ks * 4 + q) ^ (lm & 7)) * 8)];
            }
#pragma unroll
            for (int nt = 0; nt < NT; ++nt) {
                int r = wave * WN + nt * 16 + lm;
                bfr[nt] = *(const bf16_8*)&Bs[r * BK + (((ks * 4 + q) ^ (lm & 7)) * 8)];
            }
#pragma unroll
            for (int mt = 0; mt < 4; ++mt)
#pragma unroll
                for (int nt = 0; nt < NT; ++nt)
                    acc[mt][nt] = __builtin_amdgcn_mfma_f32_16x16x32_bf16(
                        af[mt], bfr[nt], acc[mt][nt], 0, 0, 0);
        }
    }

    // epilogue: D row = mBase + mt*16 + q*4 + r ; D col = nBase + wave*WN + nt*16 + lm
    const int colBase = nBase + wave * WN;
#pragma unroll
    for (int nt = 0; nt < NT; ++nt) {
        int col = colBase + nt * 16 + lm;
        float cb = 0.f, cscale = 1.f, cshift = 0.f;
        if (mode == 4) {
            float sc = bng[col] * rsqrtf(bnv[col] + 1e-5f);
            cscale = sc;
            cshift = bnb[col] - bnm[col] * sc;
            cb = bias[col];
        } else if ((mode == 0 || mode == 2) && bias && !biasRow) {
            cb = bias[col];
        }
#pragma unroll
        for (int mt = 0; mt < 4; ++mt) {
#pragma unroll
            for (int r = 0; r < 4; ++r) {
                int row = mBase + mt * 16 + q * 4 + r;
                float v = acc[mt][nt][r];
                if (mode == 1) {
                    atomicAdd(&outF[(size_t)batch * sC + (size_t)row * ldc + col], v);
                } else if (mode == 0) {
                    float bb = cb + ((bias && biasRow) ? bias[row] : 0.f);
                    outB[(size_t)batch * sC + (size_t)row * ldc + col] = f2bf(v + bb);
                } else if (mode == 2) {
                    // T2 fold: [n][c] -> [(n&2047)][2c + (n>>11)], ld 128
                    outB[(size_t)batch * sC + (size_t)(row & 2047) * 128 + 2 * col + (row >> 11)] =
                        f2bf(v + cb);
                } else if (mode == 3) {
                    // Y fold: D[m2][c2] -> Ync[((c2&1)<<11)+m2][c2>>1], ld 64
                    int n = ((col & 1) << 11) + row;
                    outB[(size_t)batch * sC + (size_t)n * 64 + (col >> 1)] = f2bf(v);
                } else { // mode 4
                    size_t o = (size_t)batch * sC + (size_t)row * ldc + col;
                    float res = bf2f(resB[(size_t)batch * sR + (size_t)row * ldc + col]);
                    outB[o] = f2bf((v + cb) * cscale + cshift + res);
                }
            }
        }
    }
}

// ---------------------------------------------------------------------------
// transpose + cast: in [b][C][4096] f32 -> out [b][4096][C] bf16
// ---------------------------------------------------------------------------
__global__ __launch_bounds__(256)
void tcast(const float* __restrict__ in, u16* __restrict__ out, int C)
{
    __shared__ u16 T[64][68];
    const int b = blockIdx.z;
    const int cb = blockIdx.y * 64;
    const int nb = blockIdx.x * 64;
    const int tid = threadIdx.x;
    {
        int nl = tid & 63, cq = tid >> 6;
#pragma unroll
        for (int i = 0; i < 16; ++i) {
            int c = cq * 16 + i;
            float v = in[(size_t)b * C * NPIX + (size_t)(cb + c) * NPIX + nb + nl];
            T[c][nl] = f2bf(v);
        }
    }
    __syncthreads();
    {
        int cl = tid & 63, nq = tid >> 6;
#pragma unroll
        for (int i = 0; i < 16; ++i) {
            int n = nq * 16 + i;
            out[(size_t)b * NPIX * C + (size_t)(nb + n) * C + cb + cl] = T[cl][n];
        }
    }
}

// cast 8 weight matrices f32 -> bf16 into one packed buffer
__global__ __launch_bounds__(256)
void wcast(const float* w0, const float* w1, const float* w2, const float* w3,
           const float* w4, const float* w5, const float* w6, const float* w7,
           u16* __restrict__ out)
{
    int i = blockIdx.x * 256 + threadIdx.x;
    if (i >= 147456) return;
    float v;
    if      (i < 32768)  v = w0[i];
    else if (i < 49152)  v = w1[i - 32768];
    else if (i < 65536)  v = w2[i - 49152];
    else if (i < 98304)  v = w3[i - 65536];
    else if (i < 106496) v = w4[i - 98304];
    else if (i < 114688) v = w5[i - 106496];
    else if (i < 131072) v = w6[i - 114688];
    else                 v = w7[i - 131072];
    out[i] = f2bf(v);
}

__global__ void zero_f32(float* p, int n)
{
    int i = blockIdx.x * 256 + threadIdx.x;
    if (i < n) p[i] = 0.f;
}

__global__ void cast_scale(const float* __restrict__ in, u16* __restrict__ out,
                           float alpha, int n)
{
    int i = blockIdx.x * 256 + threadIdx.x;
    if (i < n) out[i] = f2bf(in[i] * alpha);
}

// mean-sum & max over pixels per (b,c); z bf16 [b][n][256]
__global__ __launch_bounds__(256)
void colwise_mean_max(const u16* __restrict__ z, float* __restrict__ meanS,
                      u32* __restrict__ maxU)
{
    const int b = blockIdx.y;
    const int nb = blockIdx.x * 256;
    const int c = threadIdx.x;
    float s = 0.f, m = -1e30f;
    const u16* p = z + (size_t)b * CH * NPIX + (size_t)nb * CH + c;
    for (int i = 0; i < 256; ++i) {
        float v = bf2f(p[(size_t)i * CH]);
        s += v;
        m = fmaxf(m, v);
    }
    atomicAdd(&meanS[b * CH + c], s);
    atomicMax(&maxU[b * CH + c], encF(m));
}

__global__ __launch_bounds__(256)
void ca_mlp(const float* __restrict__ meanS, const u32* __restrict__ maxU,
            const float* __restrict__ fc1, const float* __restrict__ fc2,
            float* __restrict__ ca)
{
    const int b = blockIdx.x, tid = threadIdx.x;
    __shared__ float s_avg[CH], s_mx[CH], s_h[HID];
    s_avg[tid] = meanS[b * CH + tid] * (1.f / NPIX);
    s_mx[tid]  = decF(maxU[b * CH + tid]);
    __syncthreads();
    if (tid < HID) {
        float ha = 0.f, hm = 0.f;
        for (int c = 0; c < CH; ++c) {
            float w = fc1[tid * CH + c];
            ha += w * s_avg[c];
            hm += w * s_mx[c];
        }
        s_h[tid] = fmaxf(ha, 0.f) + fmaxf(hm, 0.f);
    }
    __syncthreads();
    float o = 0.f;
#pragma unroll
    for (int h = 0; h < HID; ++h) o += fc2[tid * HID + h] * s_h[h];
    ca[b * CH + tid] = 1.f / (1.f + expf(-o));
}

// sa_in[b,0,n]=mean_c(z*ca), sa_in[b,1,n]=max_c(z*ca); z bf16 [n][256]
__global__ __launch_bounds__(256)
void sa_input(const u16* __restrict__ z, const float* __restrict__ ca,
              float* __restrict__ sain)
{
    __shared__ float s_ca[CH];
    const int b = blockIdx.y;
    const int tid = threadIdx.x;
    s_ca[tid] = ca[b * CH + tid];
    __syncthreads();
    const int n = blockIdx.x * 256 + tid;
    const uint4* zr = (const uint4*)(z + (size_t)b * CH * NPIX + (size_t)n * CH);
    float s = 0.f, m = -1e30f;
#pragma unroll 4
    for (int i = 0; i < 32; ++i) {
        uint4 v = zr[i];
        u32 ws[4] = {v.x, v.y, v.z, v.w};
#pragma unroll
        for (int j = 0; j < 4; ++j) {
            float a  = __uint_as_float(ws[j] << 16)         * s_ca[i * 8 + j * 2];
            float c2 = __uint_as_float(ws[j] & 0xFFFF0000u) * s_ca[i * 8 + j * 2 + 1];
            s += a + c2;
            m = fmaxf(m, fmaxf(a, c2));
        }
    }
    sain[(size_t)b * 2 * NPIX + n] = s * (1.f / CH);
    sain[(size_t)b * 2 * NPIX + NPIX + n] = m;
}

// 7x7 conv (2->1 ch, pad 3) + sigmoid
__global__ __launch_bounds__(256)
void sa_conv7(const float* __restrict__ sain, const float* __restrict__ w,
              float* __restrict__ sig)
{
    __shared__ float ws[98];
    const int tid = threadIdx.x;
    if (tid < 98) ws[tid] = w[tid];
    __syncthreads();
    const int b = blockIdx.y;
    const int n = blockIdx.x * 256 + tid;
    const int h = n >> 6, x = n & 63;
    const float* p = sain + (size_t)b * 2 * NPIX;
    float s = 0.f;
#pragma unroll
    for (int ci = 0; ci < 2; ++ci)
#pragma unroll
        for (int ky = 0; ky < 7; ++ky) {
            int yy = h + ky - 3;
            if (yy < 0 || yy >= 64) continue;
#pragma unroll
            for (int kx = 0; kx < 7; ++kx) {
                int xx = x + kx - 3;
                if (xx < 0 || xx >= 64) continue;
                s += ws[ci * 49 + ky * 7 + kx] * p[ci * NPIX + yy * 64 + xx];
            }
        }
    sig[(size_t)b * NPIX + n] = 1.f / (1.f + expf(-s));
}

// out[c][n] = fw*(z[n][c]*ca[c]*sig[n]) + (1-fw)*x[c][n]   (LDS-tiled transpose)
__global__ __launch_bounds__(256)
void fuse_out(const u16* __restrict__ z, const float* __restrict__ ca,
              const float* __restrict__ sig, const float* __restrict__ x,
              const float* __restrict__ fwp, float* __restrict__ out)
{
    __shared__ float T[64][65];
    const int b = blockIdx.z;
    const int cb = blockIdx.y * 64;
    const int nb = blockIdx.x * 64;
    const int tid = threadIdx.x;
    const float fw = fwp[0];
    {
        int cl = tid & 63, nq = tid >> 6;
        float cav = ca[b * CH + cb + cl];
#pragma unroll
        for (int i = 0; i < 16; ++i) {
            int n = nq * 16 + i;
            float v = bf2f(z[(size_t)b * CH * NPIX + (size_t)(nb + n) * CH + cb + cl]);
            T[cl][n] = v * cav * sig[(size_t)b * NPIX + nb + n];
        }
    }
    __syncthreads();
    {
        int nl = tid & 63, cq = tid >> 6;
#pragma unroll
        for (int i = 0; i < 16; ++i) {
            int c = cq * 16 + i;
            size_t o = (size_t)b * CH * NPIX + (size_t)(cb + c) * NPIX + nb + nl;
            out[o] = fw * T[c][nl] + (1.f - fw) * x[o];
        }
    }
}

extern "C" void kernel_launch(void* const* d_in, const int* in_sizes, int n_in,
                              void* d_out, int out_size, void* d_ws, size_t ws_size,
                              hipStream_t stream)
{
    const float* x        = (const float*)d_in[0];
    const float* x0       = (const float*)d_in[1];
    const float* cnl_g_w  = (const float*)d_in[2];
    const float* cnl_g_b  = (const float*)d_in[3];
    const float* cnl_th_w = (const float*)d_in[4];
    const float* cnl_th_b = (const float*)d_in[5];
    const float* cnl_ph_w = (const float*)d_in[6];
    const float* cnl_ph_b = (const float*)d_in[7];
    const float* cnl_W_w  = (const float*)d_in[8];
    const float* cnl_W_b  = (const float*)d_in[9];
    const float* cnl_bn_g = (const float*)d_in[10];
    const float* cnl_bn_b = (const float*)d_in[11];
    const float* cnl_bn_m = (const float*)d_in[12];
    const float* cnl_bn_v = (const float*)d_in[13];
    const float* pnl_g_w  = (const float*)d_in[14];
    const float* pnl_g_b  = (const float*)d_in[15];
    const float* pnl_th_w = (const float*)d_in[16];
    const float* pnl_th_b = (const float*)d_in[17];
    const float* pnl_ph_w = (const float*)d_in[18];
    const float* pnl_ph_b = (const float*)d_in[19];
    const float* pnl_W_w  = (const float*)d_in[20];
    const float* pnl_W_b  = (const float*)d_in[21];
    const float* pnl_bn_g = (const float*)d_in[22];
    const float* pnl_bn_b = (const float*)d_in[23];
    const float* pnl_bn_m = (const float*)d_in[24];
    const float* pnl_bn_v = (const float*)d_in[25];
    const float* ca_fc1   = (const float*)d_in[26];
    const float* ca_fc2   = (const float*)d_in[27];
    const float* sa_w     = (const float*)d_in[28];
    const float* fw       = (const float*)d_in[29];
    float* out = (float*)d_out;
    char* wsc  = (char*)d_ws;

    // ---- workspace layout (byte offsets), ~78 MB total ----
    u16* xTb   = (u16*)(wsc + 0);            // [8][4096][256] bf16
    u16* x0Tb  = (u16*)(wsc + 16777216);     // [8][4096][128]
    u16* thcn  = (u16*)(wsc + 25165824);     // [8][128][4096]  (reused: g2cn, p2cn)
    u16* phcn  = (u16*)(wsc + 33554432);     // [8][128][4096]  (reused: T2, Ync)
    u16* gT    = (u16*)(wsc + 41943040);     // [8][4096][128]
    u16* yT    = (u16*)(wsc + 50331648);     // [8][4096][128]
    u16* zb    = (u16*)(wsc + 58720256);     // [8][4096][256]  z_cnl -> z_pnl in place
    float* attF  = (float*)(wsc + 75497472); // [8][128][128], zeroed with SF/meanS/maxU
    float* SF    = (float*)(wsc + 76021760); // [8][128][128]
    float* meanS = (float*)(wsc + 76546048); // [8][256]
    u32*   maxU  = (u32*)  (wsc + 76554240); // [8][256]
    u16* attb  = (u16*)(wsc + 76562432);     // [8][128][128]
    u16* Sb    = (u16*)(wsc + 76824576);     // [8][128][128]
    float* ca  = (float*)(wsc + 77086720);   // [8][256]
    float* sain= (float*)(wsc + 77094912);   // [8][2][4096]
    float* sig = (float*)(wsc + 77357056);   // [8][4096]
    u16* wsb   = (u16*)(wsc + 77488128);     // packed bf16 weights
    u16* g2cn  = thcn;                       // [8][64][4096] == [8][128][2048]
    u16* p2cn  = thcn + 2097152;
    u16* T2    = phcn;                       // [8][2048][128]
    u16* Ync   = phcn + 2097152;             // [8][4096][64]

    u16* w_th = wsb + 0;        // [128][256]
    u16* w_ph = wsb + 32768;    // [128][128]
    u16* w_g  = wsb + 49152;    // [128][128]
    u16* w_z  = wsb + 65536;    // [256][128]
    u16* w_g2 = wsb + 98304;    // [64][128]
    u16* w_p2 = wsb + 106496;   // [64][128]
    u16* w_t2 = wsb + 114688;   // [64][256]
    u16* w_zp = wsb + 131072;   // [256][64]

    const dim3 blk(256);
    const long long sX  = (long long)NPIX * CH;   // 1048576
    const long long sX0 = (long long)NPIX * CL;   // 524288
    const long long sCN = (long long)CL * NPIX;   // 524288
    const long long sR2 = (long long)64 * NPIX;   // 262144
    const long long sAt = (long long)CL * CL;     // 16384

    // casts + zeroing
    tcast<<<dim3(64, 4, 8), blk, 0, stream>>>(x,  xTb,  CH);
    tcast<<<dim3(64, 2, 8), blk, 0, stream>>>(x0, x0Tb, CL);
    wcast<<<dim3(576), blk, 0, stream>>>(cnl_th_w, cnl_ph_w, cnl_g_w, cnl_W_w,
                                         pnl_g_w, pnl_ph_w, pnl_th_w, pnl_W_w, wsb);
    zero_f32<<<dim3(1040), blk, 0, stream>>>(attF, 266240); // attF|SF|meanS|maxU

    // ---- CNL ----
    // th[c][n] : A=W_th(128x256), B=xTb  -> [8][128][4096] bf16 (+row bias)
    mfma_nt<128><<<dim3(32, 2, 8), blk, 0, stream>>>(w_th, 0, 256, xTb, sX, 256,
        256, 1, 0, thcn, nullptr, sCN, 4096, cnl_th_b, 1, nullptr, nullptr, nullptr, nullptr, nullptr, 0);
    // ph[c][n] : A=W_ph(128x128), B=x0Tb
    mfma_nt<128><<<dim3(32, 2, 8), blk, 0, stream>>>(w_ph, 0, 128, x0Tb, sX0, 128,
        128, 1, 0, phcn, nullptr, sCN, 4096, cnl_ph_b, 1, nullptr, nullptr, nullptr, nullptr, nullptr, 0);
    // gT[n][c] : A=x0Tb, B=W_g (+col bias)
    mfma_nt<128><<<dim3(1, 64, 8), blk, 0, stream>>>(x0Tb, sX0, 128, w_g, 0, 128,
        128, 1, 0, gT, nullptr, sX0, 128, cnl_g_b, 0, nullptr, nullptr, nullptr, nullptr, nullptr, 0);
    // att[c][d] += th . ph (split-K 16, atomics)
    mfma_nt<128><<<dim3(1, 2, 128), blk, 0, stream>>>(thcn, sCN, 4096, phcn, sCN, 4096,
        4096, 16, 1, nullptr, attF, sAt, 128, nullptr, 0, nullptr, nullptr, nullptr, nullptr, nullptr, 0);
    cast_scale<<<dim3(512), blk, 0, stream>>>(attF, attb, 1.f / CL, 131072);
    // yT[n][c] : A=gT, B=attb (per-batch)
    mfma_nt<128><<<dim3(1, 64, 8), blk, 0, stream>>>(gT, sX0, 128, attb, sAt, 128,
        128, 1, 0, yT, nullptr, sX0, 128, nullptr, 0, nullptr, nullptr, nullptr, nullptr, nullptr, 0);
    // z_cnl[n][m] = bn(yT.W_z + b) + xTb  -> zb bf16
    mfma_nt<128><<<dim3(2, 64, 8), blk, 0, stream>>>(yT, sX0, 128, w_z, 0, 128,
        128, 1, 4, zb, nullptr, sX, 256, cnl_W_b, 0, cnl_bn_g, cnl_bn_b, cnl_bn_m, cnl_bn_v, xTb, sX);

    // ---- PNL ----
    // g2[c][n], p2[c][n] : A=W(64x128), B=x0Tb
    mfma_nt<128><<<dim3(32, 1, 8), blk, 0, stream>>>(w_g2, 0, 128, x0Tb, sX0, 128,
        128, 1, 0, g2cn, nullptr, sR2, 4096, pnl_g_b, 1, nullptr, nullptr, nullptr, nullptr, nullptr, 0);
    mfma_nt<128><<<dim3(32, 1, 8), blk, 0, stream>>>(w_p2, 0, 128, x0Tb, sX0, 128,
        128, 1, 0, p2cn, nullptr, sR2, 4096, pnl_ph_b, 1, nullptr, nullptr, nullptr, nullptr, nullptr, 0);
    // t2 -> T2 folded [m2][d2] : A=zb (4096x256), B=W_t2(64x256), mode 2
    mfma_nt<64><<<dim3(1, 64, 8), blk, 0, stream>>>(zb, sX, 256, w_t2, 0, 256,
        256, 1, 2, T2, nullptr, sR2, 128, pnl_th_b, 0, nullptr, nullptr, nullptr, nullptr, nullptr, 0);
    // S[c2][d2] += G . P  (views [128][2048], split-K 8)
    mfma_nt<128><<<dim3(1, 2, 64), blk, 0, stream>>>(g2cn, sR2, 2048, p2cn, sR2, 2048,
        2048, 8, 1, nullptr, SF, sAt, 128, nullptr, 0, nullptr, nullptr, nullptr, nullptr, nullptr, 0);
    cast_scale<<<dim3(512), blk, 0, stream>>>(SF, Sb, 1.f / 2048.f, 131072);
    // Y^T[m2][c2] = T2 . Sb -> unfolded store Ync[n][c] (mode 3)
    mfma_nt<128><<<dim3(1, 32, 8), blk, 0, stream>>>(T2, sR2, 128, Sb, sAt, 128,
        128, 1, 3, Ync, nullptr, sR2, 0, nullptr, 0, nullptr, nullptr, nullptr, nullptr, nullptr, 0);
    // z_pnl[n][m] = bn(Ync.W_zp + b) + zb  (in place over zb)
    mfma_nt<128><<<dim3(2, 64, 8), blk, 0, stream>>>(Ync, sR2, 64, w_zp, 0, 64,
        64, 1, 4, zb, nullptr, sX, 256, pnl_W_b, 0, pnl_bn_g, pnl_bn_b, pnl_bn_m, pnl_bn_v, zb, sX);

    // ---- CBAM + fusion ----
    colwise_mean_max<<<dim3(16, 8), blk, 0, stream>>>(zb, meanS, maxU);
    ca_mlp<<<dim3(8), blk, 0, stream>>>(meanS, maxU, ca_fc1, ca_fc2, ca);
    sa_input<<<dim3(16, 8), blk, 0, stream>>>(zb, ca, sain);
    sa_conv7<<<dim3(16, 8), blk, 0, stream>>>(sain, sa_w, sig);
    fuse_out<<<dim3(64, 4, 8), blk, 0, stream>>>(zb, ca, sig, x, fw, out);
}

// Round 4
// 300.953 us; speedup vs baseline: 1.7218x; 1.1726x over previous
//
#include <hip/hip_runtime.h>
#include <math.h>

typedef unsigned short u16;
typedef unsigned int   u32;
typedef __bf16 bf16_8 __attribute__((ext_vector_type(8)));
typedef float  f32x4  __attribute__((ext_vector_type(4)));

constexpr int BATCH = 8;
constexpr int CH    = 256;
constexpr int CL    = 128;
constexpr int NPIX  = 4096;
constexpr int HID   = 16;

__device__ __forceinline__ u16 f2bf(float f) {
    u32 u = __float_as_uint(f);
    u = (u + 0x7FFFu + ((u >> 16) & 1u)) >> 16;
    return (u16)u;
}
__device__ __forceinline__ float bf2f(u16 h) { return __uint_as_float((u32)h << 16); }
__device__ __forceinline__ u32 encF(float f) {
    u32 u = __float_as_uint(f);
    return u ^ (u32)(((int)u >> 31) | 0x80000000);
}
__device__ __forceinline__ float decF(u32 u) {
    return __uint_as_float((u >> 31) ? (u ^ 0x80000000u) : ~u);
}

// ---------------------------------------------------------------------------
// bf16 MFMA NT GEMM: C[b][m][n] = sum_k A[b][m][k] * B[b][n][k]
// modes: 0 = bf16 store (+bias row- or col-indexed)
//        1 = atomicAdd f32 (split-K, no LDS transpose)
//        2 = T2-fold store into [m][h][c] K-permuted layout (+col bias)
//        3 = Y-unfold store into Ync[n][c]
//        4 = (acc+bias)*bnScale+bnShift + res, store bf16
//        5 = mode 4 + fused per-channel sum/max atomics (meanS=outF, maxOut)
// ---------------------------------------------------------------------------
template<int BN>
__global__ __launch_bounds__(256, 2)
void mfma_nt(const u16* __restrict__ A, long long sA, int lda,
             const u16* __restrict__ B, long long sB, int ldb,
             int K, int nSplit, int mode,
             u16* __restrict__ outB, float* __restrict__ outF, u32* __restrict__ maxOut,
             long long sC, int ldc,
             const float* __restrict__ bias, int biasRow,
             const float* __restrict__ bng, const float* __restrict__ bnb,
             const float* __restrict__ bnm, const float* __restrict__ bnv,
             const u16* __restrict__ resB, long long sR)
{
    constexpr int BM = 64, BK = 64;
    constexpr int WN = BN / 4;     // per-wave N span
    constexpr int NT = WN / 16;    // 16-col tiles per wave
    constexpr int SMSZ = BM * BK + BN * BK;
    __shared__ __align__(16) u16 smem[SMSZ + 0];
    u16* As = smem;
    u16* Bs = smem + BM * BK;
    u16* Ct = smem;                              // epilogue reuse (BM*BN <= SMSZ)
    float* sSum = (float*)&smem[BM * BN];        // mode 5 (fits: +2KB)
    u32*   sMax = (u32*)&smem[BM * BN + 512];

    const int bz    = blockIdx.z;
    const int batch = bz / nSplit;
    const int split = bz % nSplit;
    const int kLen  = K / nSplit;
    const int kBeg  = split * kLen;

    const u16* Ab = A + (size_t)batch * sA;
    const u16* Bb = B + (size_t)batch * sB;

    const int mBase = blockIdx.y * BM;
    const int nBase = blockIdx.x * BN;
    const int tid   = threadIdx.x;
    const int wave  = tid >> 6;
    const int lane  = tid & 63;
    const int lm    = lane & 15;
    const int q     = lane >> 4;

    f32x4 acc[4][NT];
#pragma unroll
    for (int i = 0; i < 4; ++i)
#pragma unroll
        for (int j = 0; j < NT; ++j) acc[i][j] = f32x4{0.f, 0.f, 0.f, 0.f};

    const int srow = tid >> 3;   // 0..31
    const int sc8  = tid & 7;    // 16B chunk within 64-elem row

    for (int k0 = kBeg; k0 < kBeg + kLen; k0 += BK) {
        __syncthreads();
#pragma unroll
        for (int it = 0; it < 2; ++it) {
            int r = srow + it * 32;
            uint4 v = *(const uint4*)(Ab + (size_t)(mBase + r) * lda + k0 + sc8 * 8);
            *(uint4*)&As[r * BK + ((sc8 ^ (r & 7)) * 8)] = v;
        }
#pragma unroll
        for (int it = 0; it < BN / 32; ++it) {
            int r = srow + it * 32;
            uint4 v = *(const uint4*)(Bb + (size_t)(nBase + r) * ldb + k0 + sc8 * 8);
            *(uint4*)&Bs[r * BK + ((sc8 ^ (r & 7)) * 8)] = v;
        }
        __syncthreads();
#pragma unroll
        for (int ks = 0; ks < 2; ++ks) {
            bf16_8 af[4], bfr[NT];
#pragma unroll
            for (int mt = 0; mt < 4; ++mt) {
                int r = mt * 16 + lm;
                af[mt] = *(const bf16_8*)&As[r * BK + (((ks * 4 + q) ^ (lm & 7)) * 8)];
            }
#pragma unroll
            for (int nt = 0; nt < NT; ++nt) {
                int r = wave * WN + nt * 16 + lm;
                bfr[nt] = *(const bf16_8*)&Bs[r * BK + (((ks * 4 + q) ^ (lm & 7)) * 8)];
            }
#pragma unroll
            for (int mt = 0; mt < 4; ++mt)
#pragma unroll
                for (int nt = 0; nt < NT; ++nt)
                    acc[mt][nt] = __builtin_amdgcn_mfma_f32_16x16x32_bf16(
                        af[mt], bfr[nt], acc[mt][nt], 0, 0, 0);
        }
    }

    if (mode == 1) {
        // direct split-K atomics (tiny output)
#pragma unroll
        for (int nt = 0; nt < NT; ++nt) {
            int col = nBase + wave * WN + nt * 16 + lm;
#pragma unroll
            for (int mt = 0; mt < 4; ++mt)
#pragma unroll
                for (int r = 0; r < 4; ++r) {
                    int row = mBase + mt * 16 + q * 4 + r;
                    atomicAdd(&outF[(size_t)batch * sC + (size_t)row * ldc + col],
                              acc[mt][nt][r]);
                }
        }
        return;
    }

    // ---- LDS transpose: C/D frag layout -> row-major tile ----
    __syncthreads();
#pragma unroll
    for (int nt = 0; nt < NT; ++nt) {
        int lc = wave * WN + nt * 16 + lm;
#pragma unroll
        for (int mt = 0; mt < 4; ++mt)
#pragma unroll
            for (int r = 0; r < 4; ++r)
                Ct[(mt * 16 + q * 4 + r) * BN + lc] = f2bf(acc[mt][nt][r]);
    }
    __syncthreads();

    constexpr int CPR   = BN / 8;     // 8-elem chunks per row
    constexpr int RSTEP = 256 / CPR;
    constexpr int PT    = BM / RSTEP;
    const int cc  = (tid % CPR) * 8;  // column base, constant per thread
    const int lr0 = tid / CPR;

    // hoist per-column params (cc constant across i)
    float csc[8], csh[8], cbv[8];
    if (mode == 4 || mode == 5) {
#pragma unroll
        for (int j = 0; j < 8; ++j) {
            int C = nBase + cc + j;
            float sc = bng[C] * rsqrtf(bnv[C] + 1e-5f);
            csc[j] = sc;
            csh[j] = bnb[C] - bnm[C] * sc;
            cbv[j] = bias[C];
        }
    } else if ((mode == 0 || mode == 2) && bias && !biasRow) {
#pragma unroll
        for (int j = 0; j < 8; ++j) cbv[j] = bias[nBase + cc + j];
    } else {
#pragma unroll
        for (int j = 0; j < 8; ++j) cbv[j] = 0.f;
    }

    float tsum[8], tmax[8];
#pragma unroll
    for (int j = 0; j < 8; ++j) { tsum[j] = 0.f; tmax[j] = -1e30f; }

#pragma unroll
    for (int i = 0; i < PT; ++i) {
        int lr = lr0 + i * RSTEP;
        int R  = mBase + lr;
        uint4 raw = *(const uint4*)&Ct[lr * BN + cc];
        u32 w[4] = {raw.x, raw.y, raw.z, raw.w};
        float v[8];
#pragma unroll
        for (int jj = 0; jj < 4; ++jj) {
            v[2 * jj]     = bf2f((u16)(w[jj] & 0xFFFFu));
            v[2 * jj + 1] = bf2f((u16)(w[jj] >> 16));
        }
        if (mode == 0) {
            float rb = (bias && biasRow) ? bias[R] : 0.f;
            u32 o[4];
#pragma unroll
            for (int jj = 0; jj < 4; ++jj) {
                u16 lo = f2bf(v[2 * jj] + cbv[2 * jj] + rb);
                u16 hi = f2bf(v[2 * jj + 1] + cbv[2 * jj + 1] + rb);
                o[jj] = (u32)lo | ((u32)hi << 16);
            }
            *(uint4*)&outB[(size_t)batch * sC + (size_t)R * ldc + nBase + cc] =
                make_uint4(o[0], o[1], o[2], o[3]);
        } else if (mode == 2) {
            // theta[c][n] -> T2f[m=n&2047][h=n>>11][c], row stride 128
            u32 o[4];
#pragma unroll
            for (int jj = 0; jj < 4; ++jj) {
                u16 lo = f2bf(v[2 * jj] + cbv[2 * jj]);
                u16 hi = f2bf(v[2 * jj + 1] + cbv[2 * jj + 1]);
                o[jj] = (u32)lo | ((u32)hi << 16);
            }
            size_t off = (size_t)batch * sC + (size_t)(R & 2047) * 128 + (R >> 11) * 64 + cc;
            *(uint4*)&outB[off] = make_uint4(o[0], o[1], o[2], o[3]);
        } else if (mode == 3) {
            // D[m][c2] -> Ync[(c2&1)*2048+m][c2>>1]; cc even => j even -> n=R, j odd -> n=R+2048
            u16 ev[4], od[4];
#pragma unroll
            for (int jj = 0; jj < 4; ++jj) {
                ev[jj] = f2bf(v[2 * jj]);
                od[jj] = f2bf(v[2 * jj + 1]);
            }
            int c0 = (cc >> 1);
            u32 e0 = (u32)ev[0] | ((u32)ev[1] << 16), e1 = (u32)ev[2] | ((u32)ev[3] << 16);
            u32 d0 = (u32)od[0] | ((u32)od[1] << 16), d1 = (u32)od[2] | ((u32)od[3] << 16);
            *(uint2*)&outB[(size_t)batch * sC + (size_t)R * 64 + c0] = make_uint2(e0, e1);
            *(uint2*)&outB[(size_t)batch * sC + (size_t)(R + 2048) * 64 + c0] = make_uint2(d0, d1);
        } else { // mode 4 / 5
            size_t off = (size_t)batch * sC + (size_t)R * ldc + nBase + cc;
            uint4 rr = *(const uint4*)&resB[(size_t)batch * sR + (size_t)R * ldc + nBase + cc];
            u32 rw[4] = {rr.x, rr.y, rr.z, rr.w};
            u32 o[4];
#pragma unroll
            for (int jj = 0; jj < 4; ++jj) {
                float z0 = (v[2 * jj] + cbv[2 * jj]) * csc[2 * jj] + csh[2 * jj] +
                           bf2f((u16)(rw[jj] & 0xFFFFu));
                float z1 = (v[2 * jj + 1] + cbv[2 * jj + 1]) * csc[2 * jj + 1] + csh[2 * jj + 1] +
                           bf2f((u16)(rw[jj] >> 16));
                u16 lo = f2bf(z0), hi = f2bf(z1);
                o[jj] = (u32)lo | ((u32)hi << 16);
                tsum[2 * jj] += bf2f(lo);  tsum[2 * jj + 1] += bf2f(hi);
                tmax[2 * jj]   = fmaxf(tmax[2 * jj], bf2f(lo));
                tmax[2 * jj + 1] = fmaxf(tmax[2 * jj + 1], bf2f(hi));
            }
            *(uint4*)&outB[off] = make_uint4(o[0], o[1], o[2], o[3]);
        }
    }

    if (mode == 5) {
        sSum[tid] = 0.f; sMax[tid] = 0u;
        __syncthreads();
#pragma unroll
        for (int j = 0; j < 8; ++j) {
            atomicAdd(&sSum[cc + j], tsum[j]);
            atomicMax(&sMax[cc + j], encF(tmax[j]));
        }
        __syncthreads();
        atomicAdd(&outF[batch * CH + tid], sSum[tid]);
        atomicMax(&maxOut[batch * CH + tid], sMax[tid]);
    }
}

// ---------------------------------------------------------------------------
// merged transpose+cast: x [b][256][4096] f32 -> xTb [b][4096][256] bf16 (y<4)
//                        x0 [b][128][4096] -> x0Tb [b][4096][128]      (y>=4)
// ---------------------------------------------------------------------------
__global__ __launch_bounds__(256)
void tcast2(const float* __restrict__ x, u16* __restrict__ xTb,
            const float* __restrict__ x0, u16* __restrict__ x0Tb)
{
    __shared__ u16 T[64][68];
    const int b = blockIdx.z;
    const bool isX = blockIdx.y < 4;
    const int C = isX ? 256 : 128;
    const float* in = isX ? x : x0;
    u16* out = isX ? xTb : x0Tb;
    const int cb = (isX ? blockIdx.y : blockIdx.y - 4) * 64;
    const int nb = blockIdx.x * 64;
    const int tid = threadIdx.x;
    {
        int nl = tid & 63, cq = tid >> 6;
#pragma unroll
        for (int i = 0; i < 16; ++i) {
            int c = cq * 16 + i;
            T[c][nl] = f2bf(in[(size_t)b * C * NPIX + (size_t)(cb + c) * NPIX + nb + nl]);
        }
    }
    __syncthreads();
    {
        int cl = tid & 63, nq = tid >> 6;
#pragma unroll
        for (int i = 0; i < 16; ++i) {
            int n = nq * 16 + i;
            out[(size_t)b * NPIX * C + (size_t)(nb + n) * C + cb + cl] = T[cl][n];
        }
    }
}

// prep: zero attF|SF|meanS|maxU region, cast 8 weight mats, pack pnl g/ph bias
__global__ __launch_bounds__(256)
void prep(const float* w0, const float* w1, const float* w2, const float* w3,
          const float* w4, const float* w5, const float* w6, const float* w7,
          const float* pgb, const float* ppb,
          float* __restrict__ zr, u16* __restrict__ wsb, float* __restrict__ pb128)
{
    int i = blockIdx.x * 256 + threadIdx.x;
    if (i < 266240) zr[i] = 0.f;
    int j = i - 266240;
    if (j >= 0 && j < 147456) {
        float v;
        if      (j < 32768)  v = w0[j];
        else if (j < 49152)  v = w1[j - 32768];
        else if (j < 65536)  v = w2[j - 49152];
        else if (j < 98304)  v = w3[j - 65536];
        else if (j < 106496) v = w4[j - 98304];
        else if (j < 114688) v = w5[j - 106496];
        else if (j < 131072) v = w6[j - 114688];
        else                 v = w7[j - 131072];
        wsb[j] = f2bf(v);
    }
    int k = i - 413696;
    if (k >= 0 && k < 128) pb128[k] = (k < 64) ? pgb[k] : ppb[k - 64];
}

// cast f32 -> bf16 with scale; perm=1 applies the K-permutation for Sb
__global__ void cast_scale(const float* __restrict__ in, u16* __restrict__ out,
                           float alpha, int n, int perm)
{
    int i = blockIdx.x * 256 + threadIdx.x;
    if (i >= n) return;
    int src = i;
    if (perm) {
        int d = i & 127;
        src = (i & ~127) + 2 * (d & 63) + (d >> 6);
    }
    out[i] = f2bf(in[src] * alpha);
}

__global__ __launch_bounds__(256)
void ca_mlp(const float* __restrict__ meanS, const u32* __restrict__ maxU,
            const float* __restrict__ fc1, const float* __restrict__ fc2,
            float* __restrict__ ca)
{
    const int b = blockIdx.x, tid = threadIdx.x;
    __shared__ float s_avg[CH], s_mx[CH], s_h[HID];
    s_avg[tid] = meanS[b * CH + tid] * (1.f / NPIX);
    s_mx[tid]  = decF(maxU[b * CH + tid]);
    __syncthreads();
    if (tid < HID) {
        float ha = 0.f, hm = 0.f;
        for (int c = 0; c < CH; ++c) {
            float w = fc1[tid * CH + c];
            ha += w * s_avg[c];
            hm += w * s_mx[c];
        }
        s_h[tid] = fmaxf(ha, 0.f) + fmaxf(hm, 0.f);
    }
    __syncthreads();
    float o = 0.f;
#pragma unroll
    for (int h = 0; h < HID; ++h) o += fc2[tid * HID + h] * s_h[h];
    ca[b * CH + tid] = 1.f / (1.f + expf(-o));
}

// sa_in: 4 threads/pixel, shfl-reduce; z bf16 [b][n][256]
__global__ __launch_bounds__(256)
void sa_input(const u16* __restrict__ z, const float* __restrict__ ca,
              float* __restrict__ sain)
{
    __shared__ float s_ca[CH];
    const int b = blockIdx.y;
    const int tid = threadIdx.x;
    s_ca[tid] = ca[b * CH + tid];
    __syncthreads();
    const int p = tid >> 2, part = tid & 3;
    const int n = blockIdx.x * 64 + p;
    const uint4* zr = (const uint4*)(z + ((size_t)b * NPIX + n) * CH + part * 64);
    float s = 0.f, m = -1e30f;
#pragma unroll
    for (int i = 0; i < 8; ++i) {
        uint4 v = zr[i];
        u32 w[4] = {v.x, v.y, v.z, v.w};
#pragma unroll
        for (int j = 0; j < 4; ++j) {
            int c = part * 64 + i * 8 + j * 2;
            float a = bf2f((u16)(w[j] & 0xFFFFu)) * s_ca[c];
            float d = bf2f((u16)(w[j] >> 16)) * s_ca[c + 1];
            s += a + d;
            m = fmaxf(m, fmaxf(a, d));
        }
    }
    s += __shfl_xor(s, 1); s += __shfl_xor(s, 2);
    m = fmaxf(m, __shfl_xor(m, 1)); m = fmaxf(m, __shfl_xor(m, 2));
    if (part == 0) {
        sain[(size_t)b * 2 * NPIX + n] = s * (1.f / CH);
        sain[(size_t)b * 2 * NPIX + NPIX + n] = m;
    }
}

__global__ __launch_bounds__(256)
void sa_conv7(const float* __restrict__ sain, const float* __restrict__ w,
              float* __restrict__ sig)
{
    __shared__ float ws[98];
    const int tid = threadIdx.x;
    if (tid < 98) ws[tid] = w[tid];
    __syncthreads();
    const int b = blockIdx.y;
    const int n = blockIdx.x * 256 + tid;
    const int h = n >> 6, x = n & 63;
    const float* p = sain + (size_t)b * 2 * NPIX;
    float s = 0.f;
#pragma unroll
    for (int ci = 0; ci < 2; ++ci)
#pragma unroll
        for (int ky = 0; ky < 7; ++ky) {
            int yy = h + ky - 3;
            if (yy < 0 || yy >= 64) continue;
#pragma unroll
            for (int kx = 0; kx < 7; ++kx) {
                int xx = x + kx - 3;
                if (xx < 0 || xx >= 64) continue;
                s += ws[ci * 49 + ky * 7 + kx] * p[ci * NPIX + yy * 64 + xx];
            }
        }
    sig[(size_t)b * NPIX + n] = 1.f / (1.f + expf(-s));
}

__global__ __launch_bounds__(256)
void fuse_out(const u16* __restrict__ z, const float* __restrict__ ca,
              const float* __restrict__ sig, const float* __restrict__ x,
              const float* __restrict__ fwp, float* __restrict__ out)
{
    __shared__ float T[64][65];
    const int b = blockIdx.z;
    const int cb = blockIdx.y * 64;
    const int nb = blockIdx.x * 64;
    const int tid = threadIdx.x;
    const float fw = fwp[0];
    {
        int cl = tid & 63, nq = tid >> 6;
        float cav = ca[b * CH + cb + cl];
#pragma unroll
        for (int i = 0; i < 16; ++i) {
            int n = nq * 16 + i;
            float v = bf2f(z[(size_t)b * CH * NPIX + (size_t)(nb + n) * CH + cb + cl]);
            T[cl][n] = v * cav * sig[(size_t)b * NPIX + nb + n];
        }
    }
    __syncthreads();
    {
        int nl = tid & 63, cq = tid >> 6;
#pragma unroll
        for (int i = 0; i < 16; ++i) {
            int c = cq * 16 + i;
            size_t o = (size_t)b * CH * NPIX + (size_t)(cb + c) * NPIX + nb + nl;
            out[o] = fw * T[c][nl] + (1.f - fw) * x[o];
        }
    }
}

extern "C" void kernel_launch(void* const* d_in, const int* in_sizes, int n_in,
                              void* d_out, int out_size, void* d_ws, size_t ws_size,
                              hipStream_t stream)
{
    const float* x        = (const float*)d_in[0];
    const float* x0       = (const float*)d_in[1];
    const float* cnl_g_w  = (const float*)d_in[2];
    const float* cnl_g_b  = (const float*)d_in[3];
    const float* cnl_th_w = (const float*)d_in[4];
    const float* cnl_th_b = (const float*)d_in[5];
    const float* cnl_ph_w = (const float*)d_in[6];
    const float* cnl_ph_b = (const float*)d_in[7];
    const float* cnl_W_w  = (const float*)d_in[8];
    const float* cnl_W_b  = (const float*)d_in[9];
    const float* cnl_bn_g = (const float*)d_in[10];
    const float* cnl_bn_b = (const float*)d_in[11];
    const float* cnl_bn_m = (const float*)d_in[12];
    const float* cnl_bn_v = (const float*)d_in[13];
    const float* pnl_g_b  = (const float*)d_in[15];
    const float* pnl_th_b = (const float*)d_in[17];
    const float* pnl_ph_b = (const float*)d_in[19];
    const float* pnl_W_b  = (const float*)d_in[21];
    const float* pnl_bn_g = (const float*)d_in[22];
    const float* pnl_bn_b = (const float*)d_in[23];
    const float* pnl_bn_m = (const float*)d_in[24];
    const float* pnl_bn_v = (const float*)d_in[25];
    const float* ca_fc1   = (const float*)d_in[26];
    const float* ca_fc2   = (const float*)d_in[27];
    const float* sa_w     = (const float*)d_in[28];
    const float* fw       = (const float*)d_in[29];
    float* out = (float*)d_out;
    char* wsc  = (char*)d_ws;

    // workspace layout (byte offsets)
    u16* xTb   = (u16*)(wsc + 0);            // [8][4096][256]
    u16* x0Tb  = (u16*)(wsc + 16777216);     // [8][4096][128]
    u16* g2p2  = (u16*)(wsc + 25165824);     // CNL: thcn [8][128][4096]; PNL: merged g2|p2
    u16* thcn  = g2p2;
    u16* phcn  = (u16*)(wsc + 33554432);     // CNL: ph [8][128][4096]; PNL: T2f + Ync
    u16* gT    = (u16*)(wsc + 41943040);     // [8][4096][128]
    u16* yT    = (u16*)(wsc + 50331648);     // [8][4096][128]
    u16* zb    = (u16*)(wsc + 58720256);     // [8][4096][256] z_cnl -> z_pnl in place
    float* attF  = (float*)(wsc + 75497472); // [8][128][128]   (zero region start)
    float* SF    = (float*)(wsc + 76021760); // [8][128][128]
    float* meanS = (float*)(wsc + 76546048); // [8][256]
    u32*   maxU  = (u32*)  (wsc + 76554240); // [8][256]        (zero region end)
    u16* attb  = (u16*)(wsc + 76562432);     // [8][128][128]
    u16* Sb    = (u16*)(wsc + 76824576);     // [8][128][128] (K-permuted)
    float* ca  = (float*)(wsc + 77086720);   // [8][256]
    float* sain= (float*)(wsc + 77094912);   // [8][2][4096]
    float* sig = (float*)(wsc + 77357056);   // [8][4096]
    u16* wsb   = (u16*)(wsc + 77488128);     // packed bf16 weights (147456)
    float* pb128 = (float*)(wsc + 77783040); // packed pnl g|ph bias
    u16* T2f   = phcn;                       // [8][2048][128] (K-permuted fold)
    u16* Ync   = phcn + 2097152;             // [8][4096][64]

    u16* w_th = wsb + 0;        // [128][256]
    u16* w_ph = wsb + 32768;    // [128][128]
    u16* w_g  = wsb + 49152;    // [128][128]
    u16* w_z  = wsb + 65536;    // [256][128]
    u16* w_gp = wsb + 98304;    // [128][128] merged g2|p2
    u16* w_t2 = wsb + 114688;   // [64][256]
    u16* w_zp = wsb + 131072;   // [256][64]

    const dim3 blk(256);
    const long long sX  = (long long)NPIX * CH;   // 1048576
    const long long sX0 = (long long)NPIX * CL;   // 524288
    const long long sCN = (long long)CL * NPIX;   // 524288
    const long long sR2 = (long long)64 * NPIX;   // 262144
    const long long sAt = (long long)CL * CL;     // 16384

    prep<<<dim3(1617), blk, 0, stream>>>(cnl_th_w, cnl_ph_w, cnl_g_w, cnl_W_w,
        (const float*)d_in[14], (const float*)d_in[18], (const float*)d_in[16],
        (const float*)d_in[20], pnl_g_b, pnl_ph_b, attF, wsb, pb128);
    tcast2<<<dim3(64, 6, 8), blk, 0, stream>>>(x, xTb, x0, x0Tb);

    // ---- CNL ----
    mfma_nt<256><<<dim3(16, 2, 8), blk, 0, stream>>>(w_th, 0, 256, xTb, sX, 256,
        256, 1, 0, thcn, nullptr, nullptr, sCN, 4096, cnl_th_b, 1,
        nullptr, nullptr, nullptr, nullptr, nullptr, 0);
    mfma_nt<256><<<dim3(16, 2, 8), blk, 0, stream>>>(w_ph, 0, 128, x0Tb, sX0, 128,
        128, 1, 0, phcn, nullptr, nullptr, sCN, 4096, cnl_ph_b, 1,
        nullptr, nullptr, nullptr, nullptr, nullptr, 0);
    mfma_nt<128><<<dim3(1, 64, 8), blk, 0, stream>>>(x0Tb, sX0, 128, w_g, 0, 128,
        128, 1, 0, gT, nullptr, nullptr, sX0, 128, cnl_g_b, 0,
        nullptr, nullptr, nullptr, nullptr, nullptr, 0);
    mfma_nt<128><<<dim3(1, 2, 128), blk, 0, stream>>>(thcn, sCN, 4096, phcn, sCN, 4096,
        4096, 16, 1, nullptr, attF, nullptr, sAt, 128, nullptr, 0,
        nullptr, nullptr, nullptr, nullptr, nullptr, 0);
    cast_scale<<<dim3(512), blk, 0, stream>>>(attF, attb, 1.f / CL, 131072, 0);
    mfma_nt<128><<<dim3(1, 64, 8), blk, 0, stream>>>(gT, sX0, 128, attb, sAt, 128,
        128, 1, 0, yT, nullptr, nullptr, sX0, 128, nullptr, 0,
        nullptr, nullptr, nullptr, nullptr, nullptr, 0);
    mfma_nt<256><<<dim3(1, 64, 8), blk, 0, stream>>>(yT, sX0, 128, w_z, 0, 128,
        128, 1, 4, zb, nullptr, nullptr, sX, 256, cnl_W_b, 0,
        cnl_bn_g, cnl_bn_b, cnl_bn_m, cnl_bn_v, xTb, sX);

    // ---- PNL ----
    mfma_nt<256><<<dim3(16, 2, 8), blk, 0, stream>>>(w_gp, 0, 128, x0Tb, sX0, 128,
        128, 1, 0, g2p2, nullptr, nullptr, sCN, 4096, pb128, 1,
        nullptr, nullptr, nullptr, nullptr, nullptr, 0);
    mfma_nt<64><<<dim3(1, 64, 8), blk, 0, stream>>>(zb, sX, 256, w_t2, 0, 256,
        256, 1, 2, T2f, nullptr, nullptr, sR2, 128, pnl_th_b, 0,
        nullptr, nullptr, nullptr, nullptr, nullptr, 0);
    mfma_nt<128><<<dim3(1, 2, 64), blk, 0, stream>>>(g2p2, sCN, 2048, g2p2 + 262144, sCN, 2048,
        2048, 8, 1, nullptr, SF, nullptr, sAt, 128, nullptr, 0,
        nullptr, nullptr, nullptr, nullptr, nullptr, 0);
    cast_scale<<<dim3(512), blk, 0, stream>>>(SF, Sb, 1.f / 2048.f, 131072, 1);
    mfma_nt<128><<<dim3(1, 32, 8), blk, 0, stream>>>(T2f, sR2, 128, Sb, sAt, 128,
        128, 1, 3, Ync, nullptr, nullptr, sR2, 64, nullptr, 0,
        nullptr, nullptr, nullptr, nullptr, nullptr, 0);
    mfma_nt<256><<<dim3(1, 64, 8), blk, 0, stream>>>(Ync, sR2, 64, w_zp, 0, 64,
        64, 1, 5, zb, meanS, maxU, sX, 256, pnl_W_b, 0,
        pnl_bn_g, pnl_bn_b, pnl_bn_m, pnl_bn_v, zb, sX);

    // ---- CBAM + fusion ----
    ca_mlp<<<dim3(8), blk, 0, stream>>>(meanS, maxU, ca_fc1, ca_fc2, ca);
    sa_input<<<dim3(64, 8), blk, 0, stream>>>(zb, ca, sain);
    sa_conv7<<<dim3(16, 8), blk, 0, stream>>>(sain, sa_w, sig);
    fuse_out<<<dim3(64, 4, 8), blk, 0, stream>>>(zb, ca, sig, x, fw, out);
}

// Round 5
// 261.740 us; speedup vs baseline: 1.9797x; 1.1498x over previous
//
#include <hip/hip_runtime.h>
#include <math.h>

typedef unsigned short u16;
typedef unsigned int   u32;
typedef __bf16 bf16_8 __attribute__((ext_vector_type(8)));
typedef float  f32x4  __attribute__((ext_vector_type(4)));

constexpr int CH   = 256;
constexpr int NPIX = 4096;

__device__ __forceinline__ u16 f2bf(float f) {
    u32 u = __float_as_uint(f);
    u = (u + 0x7FFFu + ((u >> 16) & 1u)) >> 16;
    return (u16)u;
}
__device__ __forceinline__ float bf2f(u16 h) { return __uint_as_float((u32)h << 16); }
__device__ __forceinline__ u32 encF(float f) {
    u32 u = __float_as_uint(f);
    return u ^ (u32)(((int)u >> 31) | 0x80000000);
}
__device__ __forceinline__ float decF(u32 u) {
    return __uint_as_float((u >> 31) ? (u ^ 0x80000000u) : ~u);
}

// ---------------------------------------------------------------------------
// Multi-job bf16 MFMA NT GEMM. C[b][m][n] = sum_k A[b][m][k]*B[b][n][k]
// modes: 0=bf16 store(+bias row/col), 1=atomicAdd f32 split-K,
//        3=Y-unfold store, 4=BN+res epilogue, 5=mode4+channel sum/max atomics
// ---------------------------------------------------------------------------
struct GJob {
    const u16* A; const u16* B;
    u16* outB; float* outF; u32* maxOut;
    const float* bias; const float* bng; const float* bnb; const float* bnm;
    const float* bnv; const u16* resB;
    long long sA, sB, sC, sR;
    int lda, ldb, ldc, K, nSplit, mode, biasRow, gx, gy, nBlk;
};
struct GJobs { GJob j[4]; int n; };

template<int BN>
__global__ __launch_bounds__(256, 2)
void mfma_multi(GJobs jobs)
{
    constexpr int BM = 64, BK = 64;
    constexpr int WN = BN / 4;
    constexpr int NT = WN / 16;
    __shared__ __align__(16) u16 smem[BM * BK + BN * BK];
    u16* As = smem;
    u16* Bs = smem + BM * BK;
    u16* Ct = smem;
    float* sSum = (float*)&smem[BM * BN];
    u32*   sMax = (u32*)&smem[BM * BN + 512];

    int ji = 0, start = 0;
    {
        int bxx = blockIdx.x;
        while (ji + 1 < jobs.n && bxx >= start + jobs.j[ji].nBlk) {
            start += jobs.j[ji].nBlk; ++ji;
        }
    }
    const GJob J = jobs.j[ji];
    const int local = blockIdx.x - start;
    const int per = J.gx * J.gy;
    const int bz = local / per;
    const int r2 = local - bz * per;
    const int by = r2 / J.gx;
    const int bx2 = r2 - by * J.gx;
    const int batch = bz / J.nSplit;
    const int split = bz - batch * J.nSplit;
    const int kLen = J.K / J.nSplit;
    const int kBeg = split * kLen;

    const u16* Ab = J.A + (size_t)batch * J.sA;
    const u16* Bb = J.B + (size_t)batch * J.sB;
    const int mBase = by * BM;
    const int nBase = bx2 * BN;
    const int tid = threadIdx.x;
    const int wave = tid >> 6, lane = tid & 63, lm = lane & 15, q = lane >> 4;

    f32x4 acc[4][NT];
#pragma unroll
    for (int i = 0; i < 4; ++i)
#pragma unroll
        for (int j = 0; j < NT; ++j) acc[i][j] = f32x4{0.f, 0.f, 0.f, 0.f};

    const int srow = tid >> 3, sc8 = tid & 7;

    for (int k0 = kBeg; k0 < kBeg + kLen; k0 += BK) {
        __syncthreads();
#pragma unroll
        for (int it = 0; it < 2; ++it) {
            int r = srow + it * 32;
            uint4 v = *(const uint4*)(Ab + (size_t)(mBase + r) * J.lda + k0 + sc8 * 8);
            *(uint4*)&As[r * BK + ((sc8 ^ (r & 7)) * 8)] = v;
        }
#pragma unroll
        for (int it = 0; it < BN / 32; ++it) {
            int r = srow + it * 32;
            uint4 v = *(const uint4*)(Bb + (size_t)(nBase + r) * J.ldb + k0 + sc8 * 8);
            *(uint4*)&Bs[r * BK + ((sc8 ^ (r & 7)) * 8)] = v;
        }
        __syncthreads();
#pragma unroll
        for (int ks = 0; ks < 2; ++ks) {
            bf16_8 af[4], bfr[NT];
#pragma unroll
            for (int mt = 0; mt < 4; ++mt) {
                int r = mt * 16 + lm;
                af[mt] = *(const bf16_8*)&As[r * BK + (((ks * 4 + q) ^ (lm & 7)) * 8)];
            }
#pragma unroll
            for (int nt = 0; nt < NT; ++nt) {
                int r = wave * WN + nt * 16 + lm;
                bfr[nt] = *(const bf16_8*)&Bs[r * BK + (((ks * 4 + q) ^ (lm & 7)) * 8)];
            }
#pragma unroll
            for (int mt = 0; mt < 4; ++mt)
#pragma unroll
                for (int nt = 0; nt < NT; ++nt)
                    acc[mt][nt] = __builtin_amdgcn_mfma_f32_16x16x32_bf16(
                        af[mt], bfr[nt], acc[mt][nt], 0, 0, 0);
        }
    }

    if (J.mode == 1) {
#pragma unroll
        for (int nt = 0; nt < NT; ++nt) {
            int col = nBase + wave * WN + nt * 16 + lm;
#pragma unroll
            for (int mt = 0; mt < 4; ++mt)
#pragma unroll
                for (int r = 0; r < 4; ++r) {
                    int row = mBase + mt * 16 + q * 4 + r;
                    atomicAdd(&J.outF[(size_t)batch * J.sC + (size_t)row * J.ldc + col],
                              acc[mt][nt][r]);
                }
        }
        return;
    }

    __syncthreads();
#pragma unroll
    for (int nt = 0; nt < NT; ++nt) {
        int lc = wave * WN + nt * 16 + lm;
#pragma unroll
        for (int mt = 0; mt < 4; ++mt)
#pragma unroll
            for (int r = 0; r < 4; ++r)
                Ct[(mt * 16 + q * 4 + r) * BN + lc] = f2bf(acc[mt][nt][r]);
    }
    __syncthreads();

    constexpr int CPR = BN / 8;
    constexpr int RSTEP = 256 / CPR;
    constexpr int PT = BM / RSTEP;
    const int cc = (tid % CPR) * 8;
    const int lr0 = tid / CPR;

    float csc[8], csh[8], cbv[8];
    if (J.mode == 4 || J.mode == 5) {
#pragma unroll
        for (int j = 0; j < 8; ++j) {
            int C = nBase + cc + j;
            float sc = J.bng[C] * rsqrtf(J.bnv[C] + 1e-5f);
            csc[j] = sc;
            csh[j] = J.bnb[C] - J.bnm[C] * sc;
            cbv[j] = J.bias[C];
        }
    } else if (J.mode == 0 && J.bias && !J.biasRow) {
#pragma unroll
        for (int j = 0; j < 8; ++j) cbv[j] = J.bias[nBase + cc + j];
    } else {
#pragma unroll
        for (int j = 0; j < 8; ++j) cbv[j] = 0.f;
    }

    float tsum[8], tmax[8];
#pragma unroll
    for (int j = 0; j < 8; ++j) { tsum[j] = 0.f; tmax[j] = -1e30f; }

#pragma unroll
    for (int i = 0; i < PT; ++i) {
        int lr = lr0 + i * RSTEP;
        int R = mBase + lr;
        uint4 raw = *(const uint4*)&Ct[lr * BN + cc];
        u32 w[4] = {raw.x, raw.y, raw.z, raw.w};
        float v[8];
#pragma unroll
        for (int jj = 0; jj < 4; ++jj) {
            v[2 * jj]     = bf2f((u16)(w[jj] & 0xFFFFu));
            v[2 * jj + 1] = bf2f((u16)(w[jj] >> 16));
        }
        if (J.mode == 0) {
            float rb = (J.bias && J.biasRow) ? J.bias[R] : 0.f;
            u32 o[4];
#pragma unroll
            for (int jj = 0; jj < 4; ++jj) {
                u16 lo = f2bf(v[2 * jj] + cbv[2 * jj] + rb);
                u16 hi = f2bf(v[2 * jj + 1] + cbv[2 * jj + 1] + rb);
                o[jj] = (u32)lo | ((u32)hi << 16);
            }
            *(uint4*)&J.outB[(size_t)batch * J.sC + (size_t)R * J.ldc + nBase + cc] =
                make_uint4(o[0], o[1], o[2], o[3]);
        } else if (J.mode == 3) {
            u16 ev[4], od[4];
#pragma unroll
            for (int jj = 0; jj < 4; ++jj) {
                ev[jj] = f2bf(v[2 * jj]);
                od[jj] = f2bf(v[2 * jj + 1]);
            }
            int c0 = (cc >> 1);
            u32 e0 = (u32)ev[0] | ((u32)ev[1] << 16), e1 = (u32)ev[2] | ((u32)ev[3] << 16);
            u32 d0 = (u32)od[0] | ((u32)od[1] << 16), d1 = (u32)od[2] | ((u32)od[3] << 16);
            *(uint2*)&J.outB[(size_t)batch * J.sC + (size_t)R * 64 + c0] = make_uint2(e0, e1);
            *(uint2*)&J.outB[(size_t)batch * J.sC + (size_t)(R + 2048) * 64 + c0] = make_uint2(d0, d1);
        } else { // 4 / 5
            size_t off = (size_t)batch * J.sC + (size_t)R * J.ldc + nBase + cc;
            uint4 rr = *(const uint4*)&J.resB[(size_t)batch * J.sR + (size_t)R * J.ldc + nBase + cc];
            u32 rw[4] = {rr.x, rr.y, rr.z, rr.w};
            u32 o[4];
#pragma unroll
            for (int jj = 0; jj < 4; ++jj) {
                float z0 = (v[2 * jj] + cbv[2 * jj]) * csc[2 * jj] + csh[2 * jj] +
                           bf2f((u16)(rw[jj] & 0xFFFFu));
                float z1 = (v[2 * jj + 1] + cbv[2 * jj + 1]) * csc[2 * jj + 1] +
                           csh[2 * jj + 1] + bf2f((u16)(rw[jj] >> 16));
                u16 lo = f2bf(z0), hi = f2bf(z1);
                o[jj] = (u32)lo | ((u32)hi << 16);
                tsum[2 * jj] += bf2f(lo); tsum[2 * jj + 1] += bf2f(hi);
                tmax[2 * jj] = fmaxf(tmax[2 * jj], bf2f(lo));
                tmax[2 * jj + 1] = fmaxf(tmax[2 * jj + 1], bf2f(hi));
            }
            *(uint4*)&J.outB[off] = make_uint4(o[0], o[1], o[2], o[3]);
        }
    }

    if (J.mode == 5) {
        sSum[tid] = 0.f; sMax[tid] = 0u;
        __syncthreads();
#pragma unroll
        for (int j = 0; j < 8; ++j) {
            atomicAdd(&sSum[cc + j], tsum[j]);
            atomicMax(&sMax[cc + j], encF(tmax[j]));
        }
        __syncthreads();
        atomicAdd(&J.outF[batch * CH + tid], sSum[tid]);
        atomicMax(&J.maxOut[batch * CH + tid], sMax[tid]);
    }
}

// ---------------------------------------------------------------------------
// Fused z_cnl (yT*W_z + BN + res) -> zb  AND  t2 conv (z*W_t2) -> T2f
// BN=256 tile = full channel row per 64 pixels; stage 2 runs from LDS.
// ---------------------------------------------------------------------------
__global__ __launch_bounds__(256, 2)
void zcnl_t2(const u16* __restrict__ yTg, const u16* __restrict__ w_z,
             const u16* __restrict__ xTb, const u16* __restrict__ w_t2,
             u16* __restrict__ zb, u16* __restrict__ T2f,
             const float* __restrict__ bias,
             const float* __restrict__ bng, const float* __restrict__ bnb,
             const float* __restrict__ bnm, const float* __restrict__ bnv,
             const float* __restrict__ bias2)
{
    constexpr int BM = 64, BK = 64, BN = 256, WN = 64, NT = 4;
    constexpr int LDP = 264;   // padded stride for stage-2 LDS reads
    __shared__ __align__(16) u16 smem[33792];
    u16* As = smem;
    u16* Bs = smem + 4096;
    u16* Ct = smem;            // [64][264]
    u16* B2 = smem + 16896;    // [64][264]

    const int batch = blockIdx.z;
    const int mBase = blockIdx.y * BM;
    const int tid = threadIdx.x;
    const int wave = tid >> 6, lane = tid & 63, lm = lane & 15, q = lane >> 4;
    const u16* Ab = yTg + (size_t)batch * 524288;

    f32x4 acc[4][NT];
#pragma unroll
    for (int i = 0; i < 4; ++i)
#pragma unroll
        for (int j = 0; j < NT; ++j) acc[i][j] = f32x4{0.f, 0.f, 0.f, 0.f};

    const int srow = tid >> 3, sc8 = tid & 7;
    for (int k0 = 0; k0 < 128; k0 += BK) {
        __syncthreads();
#pragma unroll
        for (int it = 0; it < 2; ++it) {
            int r = srow + it * 32;
            uint4 v = *(const uint4*)(Ab + (size_t)(mBase + r) * 128 + k0 + sc8 * 8);
            *(uint4*)&As[r * BK + ((sc8 ^ (r & 7)) * 8)] = v;
        }
#pragma unroll
        for (int it = 0; it < 8; ++it) {
            int r = srow + it * 32;
            uint4 v = *(const uint4*)(w_z + (size_t)r * 128 + k0 + sc8 * 8);
            *(uint4*)&Bs[r * BK + ((sc8 ^ (r & 7)) * 8)] = v;
        }
        __syncthreads();
#pragma unroll
        for (int ks = 0; ks < 2; ++ks) {
            bf16_8 af[4], bfr[NT];
#pragma unroll
            for (int mt = 0; mt < 4; ++mt) {
                int r = mt * 16 + lm;
                af[mt] = *(const bf16_8*)&As[r * BK + (((ks * 4 + q) ^ (lm & 7)) * 8)];
            }
#pragma unroll
            for (int nt = 0; nt < NT; ++nt) {
                int r = wave * WN + nt * 16 + lm;
                bfr[nt] = *(const bf16_8*)&Bs[r * BK + (((ks * 4 + q) ^ (lm & 7)) * 8)];
            }
#pragma unroll
            for (int mt = 0; mt < 4; ++mt)
#pragma unroll
                for (int nt = 0; nt < NT; ++nt)
                    acc[mt][nt] = __builtin_amdgcn_mfma_f32_16x16x32_bf16(
                        af[mt], bfr[nt], acc[mt][nt], 0, 0, 0);
        }
    }

    __syncthreads();
    // transpose raw acc into padded Ct; load w_t2 into B2 (disjoint region)
#pragma unroll
    for (int nt = 0; nt < NT; ++nt) {
        int lc = wave * WN + nt * 16 + lm;
#pragma unroll
        for (int mt = 0; mt < 4; ++mt)
#pragma unroll
            for (int r = 0; r < 4; ++r)
                Ct[(mt * 16 + q * 4 + r) * LDP + lc] = f2bf(acc[mt][nt][r]);
    }
#pragma unroll
    for (int i = 0; i < 8; ++i) {
        int id = tid + i * 256;
        int r = id >> 5, ch = id & 31;
        *(uint4*)&B2[r * LDP + ch * 8] = *(const uint4*)(w_t2 + r * 256 + ch * 8);
    }
    __syncthreads();

    // epilogue 1: z = (acc+bias)*scale+shift+res -> global zb, writeback to Ct
    const int cc = (tid & 31) * 8;
    const int lr0 = tid >> 5;
    float csc[8], csh[8], cbv[8];
#pragma unroll
    for (int j = 0; j < 8; ++j) {
        int C = cc + j;
        float sc = bng[C] * rsqrtf(bnv[C] + 1e-5f);
        csc[j] = sc;
        csh[j] = bnb[C] - bnm[C] * sc;
        cbv[j] = bias[C];
    }
#pragma unroll
    for (int i = 0; i < 8; ++i) {
        int lr = lr0 + i * 8;
        int R = mBase + lr;
        uint4 raw = *(const uint4*)&Ct[lr * LDP + cc];
        u32 w[4] = {raw.x, raw.y, raw.z, raw.w};
        uint4 rr = *(const uint4*)&xTb[(size_t)batch * 1048576 + (size_t)R * 256 + cc];
        u32 rw[4] = {rr.x, rr.y, rr.z, rr.w};
        u32 o[4];
#pragma unroll
        for (int jj = 0; jj < 4; ++jj) {
            float z0 = (bf2f((u16)(w[jj] & 0xFFFFu)) + cbv[2 * jj]) * csc[2 * jj] +
                       csh[2 * jj] + bf2f((u16)(rw[jj] & 0xFFFFu));
            float z1 = (bf2f((u16)(w[jj] >> 16)) + cbv[2 * jj + 1]) * csc[2 * jj + 1] +
                       csh[2 * jj + 1] + bf2f((u16)(rw[jj] >> 16));
            o[jj] = (u32)f2bf(z0) | ((u32)f2bf(z1) << 16);
        }
        *(uint4*)&zb[(size_t)batch * 1048576 + (size_t)R * 256 + cc] =
            make_uint4(o[0], o[1], o[2], o[3]);
        *(uint4*)&Ct[lr * LDP + cc] = make_uint4(o[0], o[1], o[2], o[3]);
    }
    __syncthreads();

    // stage 2: theta[d][pix] = sum_c z[pix][c] * w_t2[d][c], d = wave*16+lm
    f32x4 acc2[4];
#pragma unroll
    for (int i = 0; i < 4; ++i) acc2[i] = f32x4{0.f, 0.f, 0.f, 0.f};
#pragma unroll
    for (int ks = 0; ks < 8; ++ks) {
        bf16_8 bf = *(const bf16_8*)&B2[(wave * 16 + lm) * LDP + ks * 32 + q * 8];
#pragma unroll
        for (int mt = 0; mt < 4; ++mt) {
            bf16_8 af = *(const bf16_8*)&Ct[(mt * 16 + lm) * LDP + ks * 32 + q * 8];
            acc2[mt] = __builtin_amdgcn_mfma_f32_16x16x32_bf16(af, bf, acc2[mt], 0, 0, 0);
        }
    }
    const int d = wave * 16 + lm;
    const float b2v = bias2[d];
#pragma unroll
    for (int mt = 0; mt < 4; ++mt)
#pragma unroll
        for (int r = 0; r < 4; ++r) {
            int pix = mBase + mt * 16 + q * 4 + r;
            T2f[(size_t)batch * 262144 + (size_t)(pix & 2047) * 128 + (pix >> 11) * 64 + d] =
                f2bf(acc2[mt][r] + b2v);
        }
}

// ---------------------------------------------------------------------------
// merged prep (zero + weight cast + bias pack) and transpose-cast of x/x0
// ---------------------------------------------------------------------------
__global__ __launch_bounds__(256)
void prep_tcast(const float* __restrict__ x, u16* __restrict__ xTb,
                const float* __restrict__ x0, u16* __restrict__ x0Tb,
                const float* w0, const float* w1, const float* w2, const float* w3,
                const float* w4, const float* w5, const float* w6, const float* w7,
                const float* pgb, const float* ppb,
                float* __restrict__ zr, u16* __restrict__ wsb, float* __restrict__ pb128)
{
    __shared__ u16 T[64][68];
    const int bx = blockIdx.x, tid = threadIdx.x;
    if (bx < 3072) {
        const int b = bx / 384, rem = bx % 384;
        const int by = rem / 64, nb = (rem % 64) * 64;
        const bool isX = by < 4;
        const int C = isX ? 256 : 128;
        const float* in = isX ? x : x0;
        u16* out = isX ? xTb : x0Tb;
        const int cb = (isX ? by : by - 4) * 64;
        {
            int nl = tid & 63, cq = tid >> 6;
#pragma unroll
            for (int i = 0; i < 16; ++i) {
                int c = cq * 16 + i;
                T[c][nl] = f2bf(in[(size_t)b * C * NPIX + (size_t)(cb + c) * NPIX + nb + nl]);
            }
        }
        __syncthreads();
        {
            int cl = tid & 63, nq = tid >> 6;
#pragma unroll
            for (int i = 0; i < 16; ++i) {
                int n = nq * 16 + i;
                out[(size_t)b * NPIX * C + (size_t)(nb + n) * C + cb + cl] = T[cl][n];
            }
        }
    } else {
        int i = (bx - 3072) * 256 + tid;
        if (i < 266240) zr[i] = 0.f;
        int j = i - 266240;
        if (j >= 0 && j < 147456) {
            float v;
            if      (j < 32768)  v = w0[j];
            else if (j < 49152)  v = w1[j - 32768];
            else if (j < 65536)  v = w2[j - 49152];
            else if (j < 98304)  v = w3[j - 65536];
            else if (j < 106496) v = w4[j - 98304];
            else if (j < 114688) v = w5[j - 106496];
            else if (j < 131072) v = w6[j - 114688];
            else                 v = w7[j - 131072];
            wsb[j] = f2bf(v);
        }
        int k = i - 413696;
        if (k >= 0 && k < 128) pb128[k] = (k < 64) ? pgb[k] : ppb[k - 64];
    }
}

// cast att (scale 1/128) and S (scale 1/2048, K-permuted) in one kernel
__global__ void cast2(const float* __restrict__ attF, u16* __restrict__ attb,
                      const float* __restrict__ SF, u16* __restrict__ Sb)
{
    int i = blockIdx.x * 256 + threadIdx.x;
    if (i < 131072) {
        attb[i] = f2bf(attF[i] * (1.f / 128.f));
    } else {
        int j = i - 131072;
        int dd = j & 127;
        int src = (j & ~127) + 2 * (dd & 63) + (dd >> 6);
        Sb[j] = f2bf(SF[src] * (1.f / 2048.f));
    }
}

// CBAM: per-block redundant ca MLP + channel mean/max over z*ca per pixel
__global__ __launch_bounds__(256)
void sa_ca(const u16* __restrict__ z, const float* __restrict__ meanS,
           const u32* __restrict__ maxU, const float* __restrict__ fc1,
           const float* __restrict__ fc2, float* __restrict__ ca,
           float* __restrict__ sain)
{
    const int b = blockIdx.y, tid = threadIdx.x;
    __shared__ float s_avg[CH], s_mx[CH], s_h[16], s_ca[CH];
    s_avg[tid] = meanS[b * CH + tid] * (1.f / NPIX);
    s_mx[tid]  = decF(maxU[b * CH + tid]);
    __syncthreads();
    if (tid < 16) {
        float ha = 0.f, hm = 0.f;
        for (int c = 0; c < CH; ++c) {
            float w = fc1[tid * CH + c];
            ha += w * s_avg[c];
            hm += w * s_mx[c];
        }
        s_h[tid] = fmaxf(ha, 0.f) + fmaxf(hm, 0.f);
    }
    __syncthreads();
    float o = 0.f;
#pragma unroll
    for (int h = 0; h < 16; ++h) o += fc2[tid * 16 + h] * s_h[h];
    float cav = 1.f / (1.f + expf(-o));
    s_ca[tid] = cav;
    if (blockIdx.x == 0) ca[b * CH + tid] = cav;
    __syncthreads();

    const int p = tid >> 2, part = tid & 3;
    const int n = blockIdx.x * 64 + p;
    const uint4* zr = (const uint4*)(z + ((size_t)b * NPIX + n) * CH + part * 64);
    float s = 0.f, m = -1e30f;
#pragma unroll
    for (int i = 0; i < 8; ++i) {
        uint4 v = zr[i];
        u32 w[4] = {v.x, v.y, v.z, v.w};
#pragma unroll
        for (int j = 0; j < 4; ++j) {
            int c = part * 64 + i * 8 + j * 2;
            float a = bf2f((u16)(w[j] & 0xFFFFu)) * s_ca[c];
            float d = bf2f((u16)(w[j] >> 16)) * s_ca[c + 1];
            s += a + d;
            m = fmaxf(m, fmaxf(a, d));
        }
    }
    s += __shfl_xor(s, 1); s += __shfl_xor(s, 2);
    m = fmaxf(m, __shfl_xor(m, 1)); m = fmaxf(m, __shfl_xor(m, 2));
    if (part == 0) {
        sain[(size_t)b * 2 * NPIX + n] = s * (1.f / CH);
        sain[(size_t)b * 2 * NPIX + NPIX + n] = m;
    }
}

// fused: 7x7 conv + sigmoid (per image row) + weighted fusion w/ transpose
__global__ __launch_bounds__(256)
void fuse_conv(const u16* __restrict__ z, const float* __restrict__ ca,
               const float* __restrict__ sain, const float* __restrict__ sa_w,
               const float* __restrict__ x, const float* __restrict__ fwp,
               float* __restrict__ out)
{
    __shared__ float ws[98];
    __shared__ float s_sig[64];
    __shared__ float T[64][65];
    const int b = blockIdx.z, cb = blockIdx.y * 64, h = blockIdx.x;
    const int nb = h * 64;
    const int tid = threadIdx.x;
    if (tid < 98) ws[tid] = sa_w[tid];
    __syncthreads();
    if (tid < 64) {
        const float* p = sain + (size_t)b * 2 * NPIX;
        float s = 0.f;
#pragma unroll
        for (int ky = 0; ky < 7; ++ky) {
            int yy = h + ky - 3;
            if (yy < 0 || yy >= 64) continue;
#pragma unroll
            for (int kx = 0; kx < 7; ++kx) {
                int xx = tid + kx - 3;
                if (xx < 0 || xx >= 64) continue;
                s += ws[ky * 7 + kx] * p[yy * 64 + xx] +
                     ws[49 + ky * 7 + kx] * p[NPIX + yy * 64 + xx];
            }
        }
        s_sig[tid] = 1.f / (1.f + expf(-s));
    }
    __syncthreads();
    const float fw = fwp[0];
    {
        int cl = tid & 63, nq = tid >> 6;
        float cav = ca[b * CH + cb + cl];
#pragma unroll
        for (int i = 0; i < 16; ++i) {
            int n = nq * 16 + i;
            float v = bf2f(z[((size_t)b * NPIX + nb + n) * CH + cb + cl]);
            T[cl][n] = v * cav * s_sig[n];
        }
    }
    __syncthreads();
    {
        int nl = tid & 63, cq = tid >> 6;
#pragma unroll
        for (int i = 0; i < 16; ++i) {
            int c = cq * 16 + i;
            size_t o = (size_t)b * CH * NPIX + (size_t)(cb + c) * NPIX + nb + nl;
            out[o] = fw * T[c][nl] + (1.f - fw) * x[o];
        }
    }
}

static GJob mkjob(const u16* A, const u16* B, u16* outB, float* outF, u32* maxOut,
                  const float* bias, const float* bng, const float* bnb,
                  const float* bnm, const float* bnv, const u16* resB,
                  long long sA, long long sB, long long sC, long long sR,
                  int lda, int ldb, int ldc, int K, int nSplit, int mode,
                  int biasRow, int gx, int gy)
{
    GJob g;
    g.A = A; g.B = B; g.outB = outB; g.outF = outF; g.maxOut = maxOut;
    g.bias = bias; g.bng = bng; g.bnb = bnb; g.bnm = bnm; g.bnv = bnv; g.resB = resB;
    g.sA = sA; g.sB = sB; g.sC = sC; g.sR = sR;
    g.lda = lda; g.ldb = ldb; g.ldc = ldc; g.K = K; g.nSplit = nSplit;
    g.mode = mode; g.biasRow = biasRow; g.gx = gx; g.gy = gy;
    g.nBlk = gx * gy * 8 * nSplit;
    return g;
}

extern "C" void kernel_launch(void* const* d_in, const int* in_sizes, int n_in,
                              void* d_out, int out_size, void* d_ws, size_t ws_size,
                              hipStream_t stream)
{
    const float* x        = (const float*)d_in[0];
    const float* x0       = (const float*)d_in[1];
    const float* cnl_g_w  = (const float*)d_in[2];
    const float* cnl_g_b  = (const float*)d_in[3];
    const float* cnl_th_w = (const float*)d_in[4];
    const float* cnl_th_b = (const float*)d_in[5];
    const float* cnl_ph_w = (const float*)d_in[6];
    const float* cnl_ph_b = (const float*)d_in[7];
    const float* cnl_W_w  = (const float*)d_in[8];
    const float* cnl_W_b  = (const float*)d_in[9];
    const float* cnl_bn_g = (const float*)d_in[10];
    const float* cnl_bn_b = (const float*)d_in[11];
    const float* cnl_bn_m = (const float*)d_in[12];
    const float* cnl_bn_v = (const float*)d_in[13];
    const float* pnl_g_w  = (const float*)d_in[14];
    const float* pnl_g_b  = (const float*)d_in[15];
    const float* pnl_th_w = (const float*)d_in[16];
    const float* pnl_th_b = (const float*)d_in[17];
    const float* pnl_ph_w = (const float*)d_in[18];
    const float* pnl_ph_b = (const float*)d_in[19];
    const float* pnl_W_w  = (const float*)d_in[20];
    const float* pnl_W_b  = (const float*)d_in[21];
    const float* pnl_bn_g = (const float*)d_in[22];
    const float* pnl_bn_b = (const float*)d_in[23];
    const float* pnl_bn_m = (const float*)d_in[24];
    const float* pnl_bn_v = (const float*)d_in[25];
    const float* ca_fc1   = (const float*)d_in[26];
    const float* ca_fc2   = (const float*)d_in[27];
    const float* sa_w     = (const float*)d_in[28];
    const float* fw       = (const float*)d_in[29];
    float* out = (float*)d_out;
    char* wsc  = (char*)d_ws;

    // workspace layout (byte offsets)
    u16* xTb   = (u16*)(wsc + 0);            // [8][4096][256]
    u16* x0Tb  = (u16*)(wsc + 16777216);     // [8][4096][128]
    u16* thcn  = (u16*)(wsc + 25165824);     // [8][128][4096]
    u16* phcn  = (u16*)(wsc + 33554432);     // [8][128][4096] (later T2f|Ync)
    u16* gT    = (u16*)(wsc + 41943040);     // [8][4096][128]
    u16* yT    = (u16*)(wsc + 50331648);     // [8][4096][128]
    u16* zb    = (u16*)(wsc + 58720256);     // [8][4096][256]
    u16* g2p2  = (u16*)(wsc + 75497472);     // [8][128][4096] merged g2|p2
    float* attF  = (float*)(wsc + 83886080); // [8][128][128]  (zero region start)
    float* SF    = (float*)(wsc + 84410368); // [8][128][128]
    float* meanS = (float*)(wsc + 84934656); // [8][256]
    u32*   maxU  = (u32*)  (wsc + 84942848); // [8][256]       (zero region end)
    u16* attb  = (u16*)(wsc + 84951040);     // [8][128][128]
    u16* Sb    = (u16*)(wsc + 85213184);     // [8][128][128] K-permuted
    float* ca  = (float*)(wsc + 85475328);   // [8][256]
    float* sain= (float*)(wsc + 85483520);   // [8][2][4096]
    u16* wsb   = (u16*)(wsc + 85745664);     // packed bf16 weights
    float* pb128 = (float*)(wsc + 86040576);
    u16* T2f   = phcn;                       // [8][2048][128] K-permuted fold
    u16* Ync   = phcn + 2097152;             // [8][4096][64]

    u16* w_th = wsb + 0;
    u16* w_ph = wsb + 32768;
    u16* w_g  = wsb + 49152;
    u16* w_z  = wsb + 65536;
    u16* w_gp = wsb + 98304;
    u16* w_t2 = wsb + 114688;
    u16* w_zp = wsb + 131072;

    const long long sX  = 1048576, sX0 = 524288, sCN = 524288, sAt = 16384;

    prep_tcast<<<dim3(4689), dim3(256), 0, stream>>>(x, xTb, x0, x0Tb,
        cnl_th_w, cnl_ph_w, cnl_g_w, cnl_W_w, pnl_g_w, pnl_ph_w, pnl_th_w, pnl_W_w,
        pnl_g_b, pnl_ph_b, attF, wsb, pb128);

    // level 1: th, ph, gT, g2p2
    GJobs L1{}; L1.n = 4;
    L1.j[0] = mkjob(w_th, xTb, thcn, 0, 0, cnl_th_b, 0, 0, 0, 0, 0,
                    0, sX, sCN, 0, 256, 256, 4096, 256, 1, 0, 1, 32, 2);
    L1.j[1] = mkjob(w_ph, x0Tb, phcn, 0, 0, cnl_ph_b, 0, 0, 0, 0, 0,
                    0, sX0, sCN, 0, 128, 128, 4096, 128, 1, 0, 1, 32, 2);
    L1.j[2] = mkjob(x0Tb, w_g, gT, 0, 0, cnl_g_b, 0, 0, 0, 0, 0,
                    sX0, 0, sX0, 0, 128, 128, 128, 128, 1, 0, 0, 1, 64);
    L1.j[3] = mkjob(w_gp, x0Tb, g2p2, 0, 0, pb128, 0, 0, 0, 0, 0,
                    0, sX0, sCN, 0, 128, 128, 4096, 128, 1, 0, 1, 32, 2);
    mfma_multi<128><<<dim3(2048), dim3(256), 0, stream>>>(L1);

    // split-K: att + S (f32 atomics)
    GJobs SK{}; SK.n = 2;
    SK.j[0] = mkjob(thcn, phcn, 0, attF, 0, 0, 0, 0, 0, 0, 0,
                    sCN, sCN, sAt, 0, 4096, 4096, 128, 4096, 16, 1, 0, 1, 2);
    SK.j[1] = mkjob(g2p2, g2p2 + 262144, 0, SF, 0, 0, 0, 0, 0, 0, 0,
                    sCN, sCN, sAt, 0, 2048, 2048, 128, 2048, 8, 1, 0, 1, 2);
    mfma_multi<128><<<dim3(384), dim3(256), 0, stream>>>(SK);

    cast2<<<dim3(1024), dim3(256), 0, stream>>>(attF, attb, SF, Sb);

    // yT = gT x attb
    GJobs JY{}; JY.n = 1;
    JY.j[0] = mkjob(gT, attb, yT, 0, 0, 0, 0, 0, 0, 0, 0,
                    sX0, sAt, sX0, 0, 128, 128, 128, 128, 1, 0, 0, 1, 64);
    mfma_multi<128><<<dim3(512), dim3(256), 0, stream>>>(JY);

    // fused z_cnl + t2 conv
    zcnl_t2<<<dim3(1, 64, 8), dim3(256), 0, stream>>>(yT, w_z, xTb, w_t2, zb, T2f,
        cnl_W_b, cnl_bn_g, cnl_bn_b, cnl_bn_m, cnl_bn_v, pnl_th_b);

    // Y = T2f x Sb (unfold -> Ync)
    GJobs JG{}; JG.n = 1;
    JG.j[0] = mkjob(T2f, Sb, Ync, 0, 0, 0, 0, 0, 0, 0, 0,
                    262144, sAt, 262144, 0, 128, 128, 64, 128, 1, 3, 0, 1, 32);
    mfma_multi<128><<<dim3(256), dim3(256), 0, stream>>>(JG);

    // z_pnl = bn(Ync x w_zp) + zb, fused channel mean/max
    GJobs JZ{}; JZ.n = 1;
    JZ.j[0] = mkjob(Ync, w_zp, zb, meanS, maxU, pnl_W_b,
                    pnl_bn_g, pnl_bn_b, pnl_bn_m, pnl_bn_v, zb,
                    262144, 0, sX, sX, 64, 64, 256, 64, 1, 5, 0, 1, 64);
    mfma_multi<256><<<dim3(512), dim3(256), 0, stream>>>(JZ);

    sa_ca<<<dim3(64, 8), dim3(256), 0, stream>>>(zb, meanS, maxU, ca_fc1, ca_fc2, ca, sain);
    fuse_conv<<<dim3(64, 4, 8), dim3(256), 0, stream>>>(zb, ca, sain, sa_w, x, fw, out);
}

// Round 6
// 245.509 us; speedup vs baseline: 2.1106x; 1.0661x over previous
//
#include <hip/hip_runtime.h>
#include <math.h>

typedef unsigned short u16;
typedef unsigned int   u32;
typedef __bf16 bf16_8 __attribute__((ext_vector_type(8)));
typedef float  f32x4  __attribute__((ext_vector_type(4)));

constexpr int CH   = 256;
constexpr int NPIX = 4096;

__device__ __forceinline__ u16 f2bf(float f) {
    u32 u = __float_as_uint(f);
    u = (u + 0x7FFFu + ((u >> 16) & 1u)) >> 16;
    return (u16)u;
}
__device__ __forceinline__ float bf2f(u16 h) { return __uint_as_float((u32)h << 16); }
__device__ __forceinline__ u32 encF(float f) {
    u32 u = __float_as_uint(f);
    return u ^ (u32)(((int)u >> 31) | 0x80000000);
}
__device__ __forceinline__ float decF(u32 u) {
    return __uint_as_float((u >> 31) ? (u ^ 0x80000000u) : ~u);
}

// ---------------------------------------------------------------------------
// Multi-job bf16 MFMA NT GEMM (modes 0 = bf16 store, 1 = split-K f32 atomics)
// ---------------------------------------------------------------------------
struct GJob {
    const u16* A; const u16* B;
    u16* outB; float* outF;
    const float* bias;
    long long sA, sB, sC;
    int lda, ldb, ldc, K, nSplit, mode, biasRow, gx, gy, nBlk;
};
struct GJobs { GJob j[4]; int n; };

template<int BN>
__global__ __launch_bounds__(256, 2)
void mfma_multi(GJobs jobs)
{
    constexpr int BM = 64, BK = 64;
    constexpr int WN = BN / 4;
    constexpr int NT = WN / 16;
    __shared__ __align__(16) u16 smem[BM * BK + BN * BK];
    u16* As = smem;
    u16* Bs = smem + BM * BK;
    u16* Ct = smem;

    int ji = 0, start = 0;
    {
        int bxx = blockIdx.x;
        while (ji + 1 < jobs.n && bxx >= start + jobs.j[ji].nBlk) {
            start += jobs.j[ji].nBlk; ++ji;
        }
    }
    const GJob J = jobs.j[ji];
    const int local = blockIdx.x - start;
    const int per = J.gx * J.gy;
    const int bz = local / per;
    const int r2 = local - bz * per;
    const int by = r2 / J.gx;
    const int bx2 = r2 - by * J.gx;
    const int batch = bz / J.nSplit;
    const int split = bz - batch * J.nSplit;
    const int kLen = J.K / J.nSplit;
    const int kBeg = split * kLen;

    const u16* Ab = J.A + (size_t)batch * J.sA;
    const u16* Bb = J.B + (size_t)batch * J.sB;
    const int mBase = by * BM;
    const int nBase = bx2 * BN;
    const int tid = threadIdx.x;
    const int wave = tid >> 6, lane = tid & 63, lm = lane & 15, q = lane >> 4;

    f32x4 acc[4][NT];
#pragma unroll
    for (int i = 0; i < 4; ++i)
#pragma unroll
        for (int j = 0; j < NT; ++j) acc[i][j] = f32x4{0.f, 0.f, 0.f, 0.f};

    const int srow = tid >> 3, sc8 = tid & 7;

    for (int k0 = kBeg; k0 < kBeg + kLen; k0 += BK) {
        __syncthreads();
#pragma unroll
        for (int it = 0; it < 2; ++it) {
            int r = srow + it * 32;
            uint4 v = *(const uint4*)(Ab + (size_t)(mBase + r) * J.lda + k0 + sc8 * 8);
            *(uint4*)&As[r * BK + ((sc8 ^ (r & 7)) * 8)] = v;
        }
#pragma unroll
        for (int it = 0; it < BN / 32; ++it) {
            int r = srow + it * 32;
            uint4 v = *(const uint4*)(Bb + (size_t)(nBase + r) * J.ldb + k0 + sc8 * 8);
            *(uint4*)&Bs[r * BK + ((sc8 ^ (r & 7)) * 8)] = v;
        }
        __syncthreads();
#pragma unroll
        for (int ks = 0; ks < 2; ++ks) {
            bf16_8 af[4], bfr[NT];
#pragma unroll
            for (int mt = 0; mt < 4; ++mt) {
                int r = mt * 16 + lm;
                af[mt] = *(const bf16_8*)&As[r * BK + (((ks * 4 + q) ^ (lm & 7)) * 8)];
            }
#pragma unroll
            for (int nt = 0; nt < NT; ++nt) {
                int r = wave * WN + nt * 16 + lm;
                bfr[nt] = *(const bf16_8*)&Bs[r * BK + (((ks * 4 + q) ^ (lm & 7)) * 8)];
            }
#pragma unroll
            for (int mt = 0; mt < 4; ++mt)
#pragma unroll
                for (int nt = 0; nt < NT; ++nt)
                    acc[mt][nt] = __builtin_amdgcn_mfma_f32_16x16x32_bf16(
                        af[mt], bfr[nt], acc[mt][nt], 0, 0, 0);
        }
    }

    if (J.mode == 1) {
#pragma unroll
        for (int nt = 0; nt < NT; ++nt) {
            int col = nBase + wave * WN + nt * 16 + lm;
#pragma unroll
            for (int mt = 0; mt < 4; ++mt)
#pragma unroll
                for (int r = 0; r < 4; ++r) {
                    int row = mBase + mt * 16 + q * 4 + r;
                    atomicAdd(&J.outF[(size_t)batch * J.sC + (size_t)row * J.ldc + col],
                              acc[mt][nt][r]);
                }
        }
        return;
    }

    __syncthreads();
#pragma unroll
    for (int nt = 0; nt < NT; ++nt) {
        int lc = wave * WN + nt * 16 + lm;
#pragma unroll
        for (int mt = 0; mt < 4; ++mt)
#pragma unroll
            for (int r = 0; r < 4; ++r)
                Ct[(mt * 16 + q * 4 + r) * BN + lc] = f2bf(acc[mt][nt][r]);
    }
    __syncthreads();

    constexpr int CPR = BN / 8;
    constexpr int RSTEP = 256 / CPR;
    constexpr int PT = BM / RSTEP;
    const int cc = (tid % CPR) * 8;
    const int lr0 = tid / CPR;

    float cbv[8];
    if (J.bias && !J.biasRow) {
#pragma unroll
        for (int j = 0; j < 8; ++j) cbv[j] = J.bias[nBase + cc + j];
    } else {
#pragma unroll
        for (int j = 0; j < 8; ++j) cbv[j] = 0.f;
    }

#pragma unroll
    for (int i = 0; i < PT; ++i) {
        int lr = lr0 + i * RSTEP;
        int R = mBase + lr;
        uint4 raw = *(const uint4*)&Ct[lr * BN + cc];
        u32 w[4] = {raw.x, raw.y, raw.z, raw.w};
        float rb = (J.bias && J.biasRow) ? J.bias[R] : 0.f;
        u32 o[4];
#pragma unroll
        for (int jj = 0; jj < 4; ++jj) {
            u16 lo = f2bf(bf2f((u16)(w[jj] & 0xFFFFu)) + cbv[2 * jj] + rb);
            u16 hi = f2bf(bf2f((u16)(w[jj] >> 16)) + cbv[2 * jj + 1] + rb);
            o[jj] = (u32)lo | ((u32)hi << 16);
        }
        *(uint4*)&J.outB[(size_t)batch * J.sC + (size_t)R * J.ldc + nBase + cc] =
            make_uint4(o[0], o[1], o[2], o[3]);
    }
}

// ---------------------------------------------------------------------------
// Y3: yT = gT x att ; z_cnl = BN(yT x W_z)+x ; t2 = z x W_t2 -> T2f
// One 64-pixel tile per block. LDS 80KB (2 blocks/CU).
// ---------------------------------------------------------------------------
__global__ __launch_bounds__(256, 2)
void y3(const u16* __restrict__ gT, const float* __restrict__ attF,
        const u16* __restrict__ w_z, const u16* __restrict__ xTb,
        const u16* __restrict__ w_t2,
        u16* __restrict__ zb, u16* __restrict__ T2f,
        const float* __restrict__ bias, const float* __restrict__ bng,
        const float* __restrict__ bnb, const float* __restrict__ bnm,
        const float* __restrict__ bnv, const float* __restrict__ bias2)
{
    __shared__ __align__(16) u16 smem[40960];
    u16* sAtt = smem;          // [2][128][64] swz; later zt [4][64][64] swz
    u16* yA   = smem + 16384;  // As [64][64] swz; later yt [2][64][64] swz
    u16* Bs   = smem + 24576;  // [256][64] swz; later w_t2 [4][64][64] swz

    const int bz = blockIdx.z, mBase = blockIdx.y * 64;
    const int tid = threadIdx.x;
    const int wave = tid >> 6, lane = tid & 63, lm = lane & 15, q = lane >> 4;
    const int srow = tid >> 3, sc8 = tid & 7;

    // stage attF -> sAtt (bf16, scale 1/128, swizzled chunks)
    {
        const float* src = attF + (size_t)bz * 16384;
#pragma unroll
        for (int i = 0; i < 8; ++i) {
            int id = tid + i * 256;
            int r = id >> 4, cg = id & 15;
            int kc = cg >> 3, c8 = cg & 7;
            const float* s = src + r * 128 + kc * 64 + c8 * 8;
            u32 o[4];
#pragma unroll
            for (int j = 0; j < 4; ++j) {
                u16 lo = f2bf(s[2 * j] * (1.f / 128.f));
                u16 hi = f2bf(s[2 * j + 1] * (1.f / 128.f));
                o[j] = (u32)lo | ((u32)hi << 16);
            }
            *(uint4*)&sAtt[kc * 8192 + r * 64 + ((c8 ^ (r & 7)) * 8)] =
                make_uint4(o[0], o[1], o[2], o[3]);
        }
    }

    // phase 1: yT tile [64 pix][128 c]
    f32x4 acc1[4][2];
#pragma unroll
    for (int i = 0; i < 4; ++i)
#pragma unroll
        for (int j = 0; j < 2; ++j) acc1[i][j] = f32x4{0.f, 0.f, 0.f, 0.f};
    for (int kc = 0; kc < 2; ++kc) {
        __syncthreads();
#pragma unroll
        for (int it = 0; it < 2; ++it) {
            int r = srow + it * 32;
            uint4 v = *(const uint4*)(gT + (size_t)bz * 524288 +
                                      (size_t)(mBase + r) * 128 + kc * 64 + sc8 * 8);
            *(uint4*)&yA[r * 64 + ((sc8 ^ (r & 7)) * 8)] = v;
        }
        __syncthreads();
#pragma unroll
        for (int ks = 0; ks < 2; ++ks) {
            bf16_8 af[4], bfr[2];
#pragma unroll
            for (int mt = 0; mt < 4; ++mt) {
                int m = mt * 16 + lm;
                af[mt] = *(const bf16_8*)&yA[m * 64 + (((ks * 4 + q) ^ (m & 7)) * 8)];
            }
#pragma unroll
            for (int nt = 0; nt < 2; ++nt) {
                int rb = wave * 32 + nt * 16 + lm;
                bfr[nt] = *(const bf16_8*)&sAtt[kc * 8192 + rb * 64 +
                                                (((ks * 4 + q) ^ (rb & 7)) * 8)];
            }
#pragma unroll
            for (int mt = 0; mt < 4; ++mt)
#pragma unroll
                for (int nt = 0; nt < 2; ++nt)
                    acc1[mt][nt] = __builtin_amdgcn_mfma_f32_16x16x32_bf16(
                        af[mt], bfr[nt], acc1[mt][nt], 0, 0, 0);
        }
    }
    __syncthreads();
    // transpose acc1 -> yt (swizzled chunks in yA region)
#pragma unroll
    for (int nt = 0; nt < 2; ++nt) {
        int pcol = wave * 32 + nt * 16 + lm;
        int kc = pcol >> 6, c = pcol & 63;
#pragma unroll
        for (int mt = 0; mt < 4; ++mt)
#pragma unroll
            for (int r = 0; r < 4; ++r) {
                int prow = mt * 16 + q * 4 + r;
                yA[kc * 4096 + prow * 64 + (((c >> 3) ^ (prow & 7)) * 8) + (c & 7)] =
                    f2bf(acc1[mt][nt][r]);
            }
    }

    // phase 2: z = yt x w_z  (N=256, K=128)
    f32x4 acc2[4][4];
#pragma unroll
    for (int i = 0; i < 4; ++i)
#pragma unroll
        for (int j = 0; j < 4; ++j) acc2[i][j] = f32x4{0.f, 0.f, 0.f, 0.f};
    for (int kc = 0; kc < 2; ++kc) {
        __syncthreads();
#pragma unroll
        for (int it = 0; it < 8; ++it) {
            int r = srow + it * 32;
            uint4 v = *(const uint4*)(w_z + (size_t)r * 128 + kc * 64 + sc8 * 8);
            *(uint4*)&Bs[r * 64 + ((sc8 ^ (r & 7)) * 8)] = v;
        }
        __syncthreads();
#pragma unroll
        for (int ks = 0; ks < 2; ++ks) {
            bf16_8 af[4], bfr[4];
#pragma unroll
            for (int mt = 0; mt < 4; ++mt) {
                int m = mt * 16 + lm;
                af[mt] = *(const bf16_8*)&yA[kc * 4096 + m * 64 +
                                             (((ks * 4 + q) ^ (m & 7)) * 8)];
            }
#pragma unroll
            for (int nt = 0; nt < 4; ++nt) {
                int rb = wave * 64 + nt * 16 + lm;
                bfr[nt] = *(const bf16_8*)&Bs[rb * 64 + (((ks * 4 + q) ^ (rb & 7)) * 8)];
            }
#pragma unroll
            for (int mt = 0; mt < 4; ++mt)
#pragma unroll
                for (int nt = 0; nt < 4; ++nt)
                    acc2[mt][nt] = __builtin_amdgcn_mfma_f32_16x16x32_bf16(
                        af[mt], bfr[nt], acc2[mt][nt], 0, 0, 0);
        }
    }
    // transpose raw acc2 -> zt (sAtt region, swizzled chunks)
#pragma unroll
    for (int nt = 0; nt < 4; ++nt) {
        int pcol = wave * 64 + nt * 16 + lm;
        int kc = pcol >> 6, c = pcol & 63;
#pragma unroll
        for (int mt = 0; mt < 4; ++mt)
#pragma unroll
            for (int r = 0; r < 4; ++r) {
                int prow = mt * 16 + q * 4 + r;
                sAtt[kc * 4096 + prow * 64 + (((c >> 3) ^ (prow & 7)) * 8) + (c & 7)] =
                    f2bf(acc2[mt][nt][r]);
            }
    }
    __syncthreads();

    // epilogue: BN + residual, store zb, write back to zt
    {
        const int cc = (tid & 31) * 8, lr0 = tid >> 5;
        float csc[8], csh[8], cbv[8];
#pragma unroll
        for (int j = 0; j < 8; ++j) {
            int C = cc + j;
            float sc = bng[C] * rsqrtf(bnv[C] + 1e-5f);
            csc[j] = sc;
            csh[j] = bnb[C] - bnm[C] * sc;
            cbv[j] = bias[C];
        }
        int kcz = cc >> 6, c8z = (cc & 63) >> 3;
#pragma unroll
        for (int i = 0; i < 8; ++i) {
            int lr = lr0 + i * 8;
            int R = mBase + lr;
            int a = kcz * 4096 + lr * 64 + ((c8z ^ (lr & 7)) * 8);
            uint4 raw = *(const uint4*)&sAtt[a];
            u32 w[4] = {raw.x, raw.y, raw.z, raw.w};
            uint4 rr = *(const uint4*)&xTb[(size_t)bz * 1048576 + (size_t)R * 256 + cc];
            u32 rw[4] = {rr.x, rr.y, rr.z, rr.w};
            u32 o[4];
#pragma unroll
            for (int jj = 0; jj < 4; ++jj) {
                float z0 = (bf2f((u16)(w[jj] & 0xFFFFu)) + cbv[2 * jj]) * csc[2 * jj] +
                           csh[2 * jj] + bf2f((u16)(rw[jj] & 0xFFFFu));
                float z1 = (bf2f((u16)(w[jj] >> 16)) + cbv[2 * jj + 1]) * csc[2 * jj + 1] +
                           csh[2 * jj + 1] + bf2f((u16)(rw[jj] >> 16));
                o[jj] = (u32)f2bf(z0) | ((u32)f2bf(z1) << 16);
            }
            *(uint4*)&zb[(size_t)bz * 1048576 + (size_t)R * 256 + cc] =
                make_uint4(o[0], o[1], o[2], o[3]);
            *(uint4*)&sAtt[a] = make_uint4(o[0], o[1], o[2], o[3]);
        }
    }
    // stage w_t2 -> Bs (4 chunks)
#pragma unroll
    for (int i = 0; i < 8; ++i) {
        int id = tid + i * 256;
        int r = id >> 5, cg = id & 31;
        int kc = cg >> 3, c8 = cg & 7;
        uint4 v = *(const uint4*)(w_t2 + r * 256 + kc * 64 + c8 * 8);
        *(uint4*)&Bs[kc * 4096 + r * 64 + ((c8 ^ (r & 7)) * 8)] = v;
    }
    __syncthreads();

    // phase 3: t2 = z x w_t2  (N=64, K=256)
    f32x4 acc3[4];
#pragma unroll
    for (int i = 0; i < 4; ++i) acc3[i] = f32x4{0.f, 0.f, 0.f, 0.f};
#pragma unroll
    for (int kc = 0; kc < 4; ++kc)
#pragma unroll
        for (int ks = 0; ks < 2; ++ks) {
            int rb = wave * 16 + lm;
            bf16_8 bf = *(const bf16_8*)&Bs[kc * 4096 + rb * 64 +
                                            (((ks * 4 + q) ^ (rb & 7)) * 8)];
#pragma unroll
            for (int mt = 0; mt < 4; ++mt) {
                int m = mt * 16 + lm;
                bf16_8 af = *(const bf16_8*)&sAtt[kc * 4096 + m * 64 +
                                                  (((ks * 4 + q) ^ (m & 7)) * 8)];
                acc3[mt] = __builtin_amdgcn_mfma_f32_16x16x32_bf16(af, bf, acc3[mt], 0, 0, 0);
            }
        }
    const int d = wave * 16 + lm;
    const float b2 = bias2[d];
#pragma unroll
    for (int mt = 0; mt < 4; ++mt)
#pragma unroll
        for (int r = 0; r < 4; ++r) {
            int pix = mBase + mt * 16 + q * 4 + r;
            T2f[(size_t)bz * 262144 + (size_t)(pix & 2047) * 128 + (pix >> 11) * 64 + d] =
                f2bf(acc3[mt][r] + b2);
        }
}

// ---------------------------------------------------------------------------
// P3: Y = T2f x S (unfold) ; z_pnl = BN(Y x W_zp)+z (in place) + mean/max
// One 64-row T2f tile (=128 pixels) per block.
// ---------------------------------------------------------------------------
__global__ __launch_bounds__(256, 2)
void p3(const u16* __restrict__ T2f, const float* __restrict__ SF,
        const u16* __restrict__ w_zp, u16* __restrict__ zb,
        float* __restrict__ meanS, u32* __restrict__ maxU,
        const float* __restrict__ bias, const float* __restrict__ bng,
        const float* __restrict__ bnb, const float* __restrict__ bnm,
        const float* __restrict__ bnv)
{
    __shared__ __align__(16) u16 smem[26624];
    u16* sS = smem;            // [2][128][64] swz; later Bs [256][64] swz / Ct [64][264]
    u16* yA = smem + 16896;    // As [64][64] swz; later yu [128][68] padded
    float* sSum = (float*)&smem[25600];
    u32*   sMax = (u32*)&smem[26112];

    const int bz = blockIdx.z, mBase2 = blockIdx.y * 64;
    const int tid = threadIdx.x;
    const int wave = tid >> 6, lane = tid & 63, lm = lane & 15, q = lane >> 4;
    const int srow = tid >> 3, sc8 = tid & 7;

    // stage SF -> sS (bf16, scale 1/2048, K-permuted, swizzled)
    {
        const float* src = SF + (size_t)bz * 16384;
#pragma unroll
        for (int i = 0; i < 8; ++i) {
            int id = tid + i * 256;
            int r = id >> 4, cg = id & 15;
            int kc = cg >> 3, c8 = cg & 7;
            int k0 = kc * 64 + c8 * 8;
            u32 o[4];
#pragma unroll
            for (int j = 0; j < 4; ++j) {
                int ka = k0 + 2 * j, kb = ka + 1;
                float va = src[r * 128 + 2 * (ka & 63) + (ka >> 6)] * (1.f / 2048.f);
                float vb = src[r * 128 + 2 * (kb & 63) + (kb >> 6)] * (1.f / 2048.f);
                o[j] = (u32)f2bf(va) | ((u32)f2bf(vb) << 16);
            }
            *(uint4*)&sS[kc * 8192 + r * 64 + ((c8 ^ (r & 7)) * 8)] =
                make_uint4(o[0], o[1], o[2], o[3]);
        }
    }

    // phase 1: Y[m2 64][c2 128] = T2f x S
    f32x4 acc1[4][2];
#pragma unroll
    for (int i = 0; i < 4; ++i)
#pragma unroll
        for (int j = 0; j < 2; ++j) acc1[i][j] = f32x4{0.f, 0.f, 0.f, 0.f};
    for (int kc = 0; kc < 2; ++kc) {
        __syncthreads();
#pragma unroll
        for (int it = 0; it < 2; ++it) {
            int r = srow + it * 32;
            uint4 v = *(const uint4*)(T2f + (size_t)bz * 262144 +
                                      (size_t)(mBase2 + r) * 128 + kc * 64 + sc8 * 8);
            *(uint4*)&yA[r * 64 + ((sc8 ^ (r & 7)) * 8)] = v;
        }
        __syncthreads();
#pragma unroll
        for (int ks = 0; ks < 2; ++ks) {
            bf16_8 af[4], bfr[2];
#pragma unroll
            for (int mt = 0; mt < 4; ++mt) {
                int m = mt * 16 + lm;
                af[mt] = *(const bf16_8*)&yA[m * 64 + (((ks * 4 + q) ^ (m & 7)) * 8)];
            }
#pragma unroll
            for (int nt = 0; nt < 2; ++nt) {
                int rb = wave * 32 + nt * 16 + lm;
                bfr[nt] = *(const bf16_8*)&sS[kc * 8192 + rb * 64 +
                                              (((ks * 4 + q) ^ (rb & 7)) * 8)];
            }
#pragma unroll
            for (int mt = 0; mt < 4; ++mt)
#pragma unroll
                for (int nt = 0; nt < 2; ++nt)
                    acc1[mt][nt] = __builtin_amdgcn_mfma_f32_16x16x32_bf16(
                        af[mt], bfr[nt], acc1[mt][nt], 0, 0, 0);
        }
    }
    __syncthreads();
    // unfold: (m2, c2) -> yu[(c2&1)*64 + m2][c2>>1], pad 68
#pragma unroll
    for (int nt = 0; nt < 2; ++nt) {
        int pcol = wave * 32 + nt * 16 + lm;
        int half = pcol & 1, ch = pcol >> 1;
#pragma unroll
        for (int mt = 0; mt < 4; ++mt)
#pragma unroll
            for (int r = 0; r < 4; ++r) {
                int prow = mt * 16 + q * 4 + r;
                yA[(half * 64 + prow) * 68 + ch] = f2bf(acc1[mt][nt][r]);
            }
    }
    // stage w_zp [256][64] -> Bs (sS region)
#pragma unroll
    for (int it = 0; it < 8; ++it) {
        int r = srow + it * 32;
        uint4 v = *(const uint4*)(w_zp + (size_t)r * 64 + sc8 * 8);
        *(uint4*)&sS[r * 64 + ((sc8 ^ (r & 7)) * 8)] = v;
    }
    __syncthreads();

    // phase 2: z[128 pix][256 ch] = yu x w_zp  (K=64)
    f32x4 acc2[8][4];
#pragma unroll
    for (int i = 0; i < 8; ++i)
#pragma unroll
        for (int j = 0; j < 4; ++j) acc2[i][j] = f32x4{0.f, 0.f, 0.f, 0.f};
#pragma unroll
    for (int ks = 0; ks < 2; ++ks) {
        bf16_8 bfr[4];
#pragma unroll
        for (int nt = 0; nt < 4; ++nt) {
            int rb = wave * 64 + nt * 16 + lm;
            bfr[nt] = *(const bf16_8*)&sS[rb * 64 + (((ks * 4 + q) ^ (rb & 7)) * 8)];
        }
#pragma unroll
        for (int mt = 0; mt < 8; ++mt) {
            int m = mt * 16 + lm;
            bf16_8 af = *(const bf16_8*)&yA[m * 68 + ks * 32 + q * 8];
#pragma unroll
            for (int nt = 0; nt < 4; ++nt)
                acc2[mt][nt] = __builtin_amdgcn_mfma_f32_16x16x32_bf16(
                    af, bfr[nt], acc2[mt][nt], 0, 0, 0);
        }
    }

    // epilogue (two 64-row halves through Ct), fused mean/max
    const int cc = (tid & 31) * 8, lr0 = tid >> 5;
    float csc[8], csh[8], cbv[8], tsum[8], tmax[8];
#pragma unroll
    for (int j = 0; j < 8; ++j) {
        int C = cc + j;
        float sc = bng[C] * rsqrtf(bnv[C] + 1e-5f);
        csc[j] = sc;
        csh[j] = bnb[C] - bnm[C] * sc;
        cbv[j] = bias[C];
        tsum[j] = 0.f; tmax[j] = -1e30f;
    }
#pragma unroll
    for (int h = 0; h < 2; ++h) {
        __syncthreads();
#pragma unroll
        for (int nt = 0; nt < 4; ++nt) {
            int pcol = wave * 64 + nt * 16 + lm;
#pragma unroll
            for (int mt = 0; mt < 4; ++mt)
#pragma unroll
                for (int r = 0; r < 4; ++r) {
                    int prow = mt * 16 + q * 4 + r;
                    sS[prow * 264 + pcol] = f2bf(acc2[h * 4 + mt][nt][r]);
                }
        }
        __syncthreads();
#pragma unroll
        for (int i = 0; i < 8; ++i) {
            int lr = lr0 + i * 8;
            int pix = h * 2048 + mBase2 + lr;
            uint4 raw = *(const uint4*)&sS[lr * 264 + cc];
            u32 w[4] = {raw.x, raw.y, raw.z, raw.w};
            size_t off = (size_t)bz * 1048576 + (size_t)pix * 256 + cc;
            uint4 rr = *(const uint4*)&zb[off];
            u32 rw[4] = {rr.x, rr.y, rr.z, rr.w};
            u32 o[4];
#pragma unroll
            for (int jj = 0; jj < 4; ++jj) {
                float z0 = (bf2f((u16)(w[jj] & 0xFFFFu)) + cbv[2 * jj]) * csc[2 * jj] +
                           csh[2 * jj] + bf2f((u16)(rw[jj] & 0xFFFFu));
                float z1 = (bf2f((u16)(w[jj] >> 16)) + cbv[2 * jj + 1]) * csc[2 * jj + 1] +
                           csh[2 * jj + 1] + bf2f((u16)(rw[jj] >> 16));
                u16 lo = f2bf(z0), hi = f2bf(z1);
                o[jj] = (u32)lo | ((u32)hi << 16);
                tsum[2 * jj] += bf2f(lo); tsum[2 * jj + 1] += bf2f(hi);
                tmax[2 * jj] = fmaxf(tmax[2 * jj], bf2f(lo));
                tmax[2 * jj + 1] = fmaxf(tmax[2 * jj + 1], bf2f(hi));
            }
            *(uint4*)&zb[off] = make_uint4(o[0], o[1], o[2], o[3]);
        }
    }
    __syncthreads();
    sSum[tid] = 0.f; sMax[tid] = 0u;
    __syncthreads();
#pragma unroll
    for (int j = 0; j < 8; ++j) {
        atomicAdd(&sSum[cc + j], tsum[j]);
        atomicMax(&sMax[cc + j], encF(tmax[j]));
    }
    __syncthreads();
    atomicAdd(&meanS[bz * CH + tid], sSum[tid]);
    atomicMax(&maxU[bz * CH + tid], sMax[tid]);
}

// ---------------------------------------------------------------------------
__global__ __launch_bounds__(256)
void prep_tcast(const float* __restrict__ x, u16* __restrict__ xTb,
                const float* __restrict__ x0, u16* __restrict__ x0Tb,
                const float* w0, const float* w1, const float* w2, const float* w3,
                const float* w4, const float* w5, const float* w6, const float* w7,
                const float* pgb, const float* ppb,
                float* __restrict__ zr, u16* __restrict__ wsb, float* __restrict__ pb128)
{
    __shared__ u16 T[64][68];
    const int bx = blockIdx.x, tid = threadIdx.x;
    if (bx < 3072) {
        const int b = bx / 384, rem = bx % 384;
        const int by = rem / 64, nb = (rem % 64) * 64;
        const bool isX = by < 4;
        const int C = isX ? 256 : 128;
        const float* in = isX ? x : x0;
        u16* out = isX ? xTb : x0Tb;
        const int cb = (isX ? by : by - 4) * 64;
        {
            int nl = tid & 63, cq = tid >> 6;
#pragma unroll
            for (int i = 0; i < 16; ++i) {
                int c = cq * 16 + i;
                T[c][nl] = f2bf(in[(size_t)b * C * NPIX + (size_t)(cb + c) * NPIX + nb + nl]);
            }
        }
        __syncthreads();
        {
            int cl = tid & 63, nq = tid >> 6;
#pragma unroll
            for (int i = 0; i < 16; ++i) {
                int n = nq * 16 + i;
                out[(size_t)b * NPIX * C + (size_t)(nb + n) * C + cb + cl] = T[cl][n];
            }
        }
    } else {
        int i = (bx - 3072) * 256 + tid;
        if (i < 266240) zr[i] = 0.f;
        int j = i - 266240;
        if (j >= 0 && j < 147456) {
            float v;
            if      (j < 32768)  v = w0[j];
            else if (j < 49152)  v = w1[j - 32768];
            else if (j < 65536)  v = w2[j - 49152];
            else if (j < 98304)  v = w3[j - 65536];
            else if (j < 106496) v = w4[j - 98304];
            else if (j < 114688) v = w5[j - 106496];
            else if (j < 131072) v = w6[j - 114688];
            else                 v = w7[j - 131072];
            wsb[j] = f2bf(v);
        }
        int k = i - 413696;
        if (k >= 0 && k < 128) pb128[k] = (k < 64) ? pgb[k] : ppb[k - 64];
    }
}

__global__ __launch_bounds__(256)
void sa_ca(const u16* __restrict__ z, const float* __restrict__ meanS,
           const u32* __restrict__ maxU, const float* __restrict__ fc1,
           const float* __restrict__ fc2, float* __restrict__ ca,
           float* __restrict__ sain)
{
    const int b = blockIdx.y, tid = threadIdx.x;
    __shared__ float s_avg[CH], s_mx[CH], s_h[16], s_ca[CH];
    s_avg[tid] = meanS[b * CH + tid] * (1.f / NPIX);
    s_mx[tid]  = decF(maxU[b * CH + tid]);
    __syncthreads();
    if (tid < 16) {
        float ha = 0.f, hm = 0.f;
        for (int c = 0; c < CH; ++c) {
            float w = fc1[tid * CH + c];
            ha += w * s_avg[c];
            hm += w * s_mx[c];
        }
        s_h[tid] = fmaxf(ha, 0.f) + fmaxf(hm, 0.f);
    }
    __syncthreads();
    float o = 0.f;
#pragma unroll
    for (int h = 0; h < 16; ++h) o += fc2[tid * 16 + h] * s_h[h];
    float cav = 1.f / (1.f + expf(-o));
    s_ca[tid] = cav;
    if (blockIdx.x == 0) ca[b * CH + tid] = cav;
    __syncthreads();

    const int p = tid >> 2, part = tid & 3;
    const int n = blockIdx.x * 64 + p;
    const uint4* zr = (const uint4*)(z + ((size_t)b * NPIX + n) * CH + part * 64);
    float s = 0.f, m = -1e30f;
#pragma unroll
    for (int i = 0; i < 8; ++i) {
        uint4 v = zr[i];
        u32 w[4] = {v.x, v.y, v.z, v.w};
#pragma unroll
        for (int j = 0; j < 4; ++j) {
            int c = part * 64 + i * 8 + j * 2;
            float a = bf2f((u16)(w[j] & 0xFFFFu)) * s_ca[c];
            float d = bf2f((u16)(w[j] >> 16)) * s_ca[c + 1];
            s += a + d;
            m = fmaxf(m, fmaxf(a, d));
        }
    }
    s += __shfl_xor(s, 1); s += __shfl_xor(s, 2);
    m = fmaxf(m, __shfl_xor(m, 1)); m = fmaxf(m, __shfl_xor(m, 2));
    if (part == 0) {
        sain[(size_t)b * 2 * NPIX + n] = s * (1.f / CH);
        sain[(size_t)b * 2 * NPIX + NPIX + n] = m;
    }
}

__global__ __launch_bounds__(256)
void fuse_conv(const u16* __restrict__ z, const float* __restrict__ ca,
               const float* __restrict__ sain, const float* __restrict__ sa_w,
               const float* __restrict__ x, const float* __restrict__ fwp,
               float* __restrict__ out)
{
    __shared__ float ws[98];
    __shared__ float s_sig[64];
    __shared__ float T[64][65];
    const int b = blockIdx.z, cb = blockIdx.y * 64, h = blockIdx.x;
    const int nb = h * 64;
    const int tid = threadIdx.x;
    if (tid < 98) ws[tid] = sa_w[tid];
    __syncthreads();
    if (tid < 64) {
        const float* p = sain + (size_t)b * 2 * NPIX;
        float s = 0.f;
#pragma unroll
        for (int ky = 0; ky < 7; ++ky) {
            int yy = h + ky - 3;
            if (yy < 0 || yy >= 64) continue;
#pragma unroll
            for (int kx = 0; kx < 7; ++kx) {
                int xx = tid + kx - 3;
                if (xx < 0 || xx >= 64) continue;
                s += ws[ky * 7 + kx] * p[yy * 64 + xx] +
                     ws[49 + ky * 7 + kx] * p[NPIX + yy * 64 + xx];
            }
        }
        s_sig[tid] = 1.f / (1.f + expf(-s));
    }
    __syncthreads();
    const float fw = fwp[0];
    {
        int cl = tid & 63, nq = tid >> 6;
        float cav = ca[b * CH + cb + cl];
#pragma unroll
        for (int i = 0; i < 16; ++i) {
            int n = nq * 16 + i;
            float v = bf2f(z[((size_t)b * NPIX + nb + n) * CH + cb + cl]);
            T[cl][n] = v * cav * s_sig[n];
        }
    }
    __syncthreads();
    {
        int nl = tid & 63, cq = tid >> 6;
#pragma unroll
        for (int i = 0; i < 16; ++i) {
            int c = cq * 16 + i;
            size_t o = (size_t)b * CH * NPIX + (size_t)(cb + c) * NPIX + nb + nl;
            out[o] = fw * T[c][nl] + (1.f - fw) * x[o];
        }
    }
}

static GJob mkjob(const u16* A, const u16* B, u16* outB, float* outF,
                  const float* bias,
                  long long sA, long long sB, long long sC,
                  int lda, int ldb, int ldc, int K, int nSplit, int mode,
                  int biasRow, int gx, int gy)
{
    GJob g;
    g.A = A; g.B = B; g.outB = outB; g.outF = outF; g.bias = bias;
    g.sA = sA; g.sB = sB; g.sC = sC;
    g.lda = lda; g.ldb = ldb; g.ldc = ldc; g.K = K; g.nSplit = nSplit;
    g.mode = mode; g.biasRow = biasRow; g.gx = gx; g.gy = gy;
    g.nBlk = gx * gy * 8 * nSplit;
    return g;
}

extern "C" void kernel_launch(void* const* d_in, const int* in_sizes, int n_in,
                              void* d_out, int out_size, void* d_ws, size_t ws_size,
                              hipStream_t stream)
{
    const float* x        = (const float*)d_in[0];
    const float* x0       = (const float*)d_in[1];
    const float* cnl_g_w  = (const float*)d_in[2];
    const float* cnl_g_b  = (const float*)d_in[3];
    const float* cnl_th_w = (const float*)d_in[4];
    const float* cnl_th_b = (const float*)d_in[5];
    const float* cnl_ph_w = (const float*)d_in[6];
    const float* cnl_ph_b = (const float*)d_in[7];
    const float* cnl_W_w  = (const float*)d_in[8];
    const float* cnl_W_b  = (const float*)d_in[9];
    const float* cnl_bn_g = (const float*)d_in[10];
    const float* cnl_bn_b = (const float*)d_in[11];
    const float* cnl_bn_m = (const float*)d_in[12];
    const float* cnl_bn_v = (const float*)d_in[13];
    const float* pnl_g_w  = (const float*)d_in[14];
    const float* pnl_g_b  = (const float*)d_in[15];
    const float* pnl_th_w = (const float*)d_in[16];
    const float* pnl_th_b = (const float*)d_in[17];
    const float* pnl_ph_w = (const float*)d_in[18];
    const float* pnl_ph_b = (const float*)d_in[19];
    const float* pnl_W_w  = (const float*)d_in[20];
    const float* pnl_W_b  = (const float*)d_in[21];
    const float* pnl_bn_g = (const float*)d_in[22];
    const float* pnl_bn_b = (const float*)d_in[23];
    const float* pnl_bn_m = (const float*)d_in[24];
    const float* pnl_bn_v = (const float*)d_in[25];
    const float* ca_fc1   = (const float*)d_in[26];
    const float* ca_fc2   = (const float*)d_in[27];
    const float* sa_w     = (const float*)d_in[28];
    const float* fw       = (const float*)d_in[29];
    float* out = (float*)d_out;
    char* wsc  = (char*)d_ws;

    u16* xTb   = (u16*)(wsc + 0);            // [8][4096][256]
    u16* x0Tb  = (u16*)(wsc + 16777216);     // [8][4096][128]
    u16* thcn  = (u16*)(wsc + 25165824);     // [8][128][4096]
    u16* phcn  = (u16*)(wsc + 33554432);     // [8][128][4096] (later T2f)
    u16* gT    = (u16*)(wsc + 41943040);     // [8][4096][128]
    u16* zb    = (u16*)(wsc + 58720256);     // [8][4096][256]
    u16* g2p2  = (u16*)(wsc + 75497472);     // [8][128][4096] merged g2|p2
    float* attF  = (float*)(wsc + 83886080); // [8][128][128] (zero region start)
    float* SF    = (float*)(wsc + 84410368); // [8][128][128]
    float* meanS = (float*)(wsc + 84934656); // [8][256]
    u32*   maxU  = (u32*)  (wsc + 84942848); // [8][256]      (zero region end)
    float* ca  = (float*)(wsc + 85475328);   // [8][256]
    float* sain= (float*)(wsc + 85483520);   // [8][2][4096]
    u16* wsb   = (u16*)(wsc + 85745664);     // packed bf16 weights
    float* pb128 = (float*)(wsc + 86040576);
    u16* T2f   = phcn;                       // [8][2048][128] K-permuted fold

    u16* w_th = wsb + 0;
    u16* w_ph = wsb + 32768;
    u16* w_g  = wsb + 49152;
    u16* w_z  = wsb + 65536;
    u16* w_gp = wsb + 98304;
    u16* w_t2 = wsb + 114688;
    u16* w_zp = wsb + 131072;

    const long long sX0 = 524288, sCN = 524288, sAt = 16384;
    const long long sX  = 1048576;

    prep_tcast<<<dim3(4689), dim3(256), 0, stream>>>(x, xTb, x0, x0Tb,
        cnl_th_w, cnl_ph_w, cnl_g_w, cnl_W_w, pnl_g_w, pnl_ph_w, pnl_th_w, pnl_W_w,
        pnl_g_b, pnl_ph_b, attF, wsb, pb128);

    // level 1: th, ph, gT, g2p2
    GJobs L1{}; L1.n = 4;
    L1.j[0] = mkjob(w_th, xTb, thcn, 0, cnl_th_b, 0, sX, sCN,
                    256, 256, 4096, 256, 1, 0, 1, 32, 2);
    L1.j[1] = mkjob(w_ph, x0Tb, phcn, 0, cnl_ph_b, 0, sX0, sCN,
                    128, 128, 4096, 128, 1, 0, 1, 32, 2);
    L1.j[2] = mkjob(x0Tb, w_g, gT, 0, cnl_g_b, sX0, 0, sX0,
                    128, 128, 128, 128, 1, 0, 0, 1, 64);
    L1.j[3] = mkjob(w_gp, x0Tb, g2p2, 0, pb128, 0, sX0, sCN,
                    128, 128, 4096, 128, 1, 0, 1, 32, 2);
    mfma_multi<128><<<dim3(2048), dim3(256), 0, stream>>>(L1);

    // split-K: att + S
    GJobs SK{}; SK.n = 2;
    SK.j[0] = mkjob(thcn, phcn, 0, attF, 0, sCN, sCN, sAt,
                    4096, 4096, 128, 4096, 16, 1, 0, 1, 2);
    SK.j[1] = mkjob(g2p2, g2p2 + 262144, 0, SF, 0, sCN, sCN, sAt,
                    2048, 2048, 128, 2048, 8, 1, 0, 1, 2);
    mfma_multi<128><<<dim3(384), dim3(256), 0, stream>>>(SK);

    // fused yT -> z_cnl -> t2
    y3<<<dim3(1, 64, 8), dim3(256), 0, stream>>>(gT, attF, w_z, xTb, w_t2, zb, T2f,
        cnl_W_b, cnl_bn_g, cnl_bn_b, cnl_bn_m, cnl_bn_v, pnl_th_b);

    // fused Y -> z_pnl (+ mean/max)
    p3<<<dim3(1, 32, 8), dim3(256), 0, stream>>>(T2f, SF, w_zp, zb, meanS, maxU,
        pnl_W_b, pnl_bn_g, pnl_bn_b, pnl_bn_m, pnl_bn_v);

    sa_ca<<<dim3(64, 8), dim3(256), 0, stream>>>(zb, meanS, maxU, ca_fc1, ca_fc2, ca, sain);
    fuse_conv<<<dim3(64, 4, 8), dim3(256), 0, stream>>>(zb, ca, sain, sa_w, x, fw, out);
}